// Round 14
// baseline (947.953 us; speedup 1.0000x reference)
//
#include <hip/hip_runtime.h>
#include <hip/hip_bf16.h>
#include <math.h>

#define B_ 16
#define N_ 500
#define T_ 12
#define K_ 10
#define NROWS (B_*N_)   // 8000
#define TROWS 6         // k_tcn rows per block

// ---------------- threefry / gumbel (jax.random.key(42)) ----------------
__device__ __forceinline__ unsigned rotl32(unsigned v, int r){ return (v<<r)|(v>>(32-r)); }

__device__ __forceinline__ void threefry2x32(unsigned k0, unsigned k1,
                                             unsigned c0, unsigned c1,
                                             unsigned &o0, unsigned &o1){
  unsigned ks2 = k0 ^ k1 ^ 0x1BD11BDAu;
  unsigned x0 = c0 + k0, x1 = c1 + k1;
#define TF_R(r) { x0 += x1; x1 = rotl32(x1,(r)); x1 ^= x0; }
  TF_R(13) TF_R(15) TF_R(26) TF_R(6)
  x0 += k1;  x1 += ks2 + 1u;
  TF_R(17) TF_R(29) TF_R(16) TF_R(24)
  x0 += ks2; x1 += k0 + 2u;
  TF_R(13) TF_R(15) TF_R(26) TF_R(6)
  x0 += k0;  x1 += k1 + 3u;
  TF_R(17) TF_R(29) TF_R(16) TF_R(24)
  x0 += k1;  x1 += ks2 + 4u;
  TF_R(13) TF_R(15) TF_R(26) TF_R(6)
  x0 += ks2; x1 += k0 + 5u;
#undef TF_R
  o0 = x0; o1 = x1;
}

// Partitionable threefry (JAX >= 0.4.30): bits[i] = x0 ^ x1 of threefry(key,(0,i)).
// VERIFIED bit-exact vs harness (round 5 pass).
__device__ __forceinline__ float gumbel_at(unsigned idx){
  unsigned b0, b1;
  threefry2x32(0u, 42u, 0u, idx, b0, b1);
  unsigned bits = b0 ^ b1;
  float u = __uint_as_float((bits >> 9) | 0x3f800000u) - 1.0f;  // [0,1)
  u = fmaxf(u, 1.17549435e-38f);
  return -logf(-logf(u));
}

// ---------------- matq = nodes_cb @ w_q ----------------
__global__ __launch_bounds__(256) void k_matq(const float* __restrict__ nodes_cb,
                                              const float* __restrict__ w_q,
                                              float* __restrict__ matq){
  int idx = blockIdx.x*256 + threadIdx.x;
  if (idx >= N_*64) return;
  int n = idx >> 6, d = idx & 63;
  float a = 0.f;
  for (int c = 0; c < 64; ++c) a += nodes_cb[n*64+c] * w_q[c*64+d];
  matq[idx] = a;
}

// ---------------- routing ----------------
__global__ __launch_bounds__(256) void k_route(const float* __restrict__ env_cb,
                                               const float* __restrict__ w_v,
                                               const float* __restrict__ w_k,
                                               const float* __restrict__ matq,
                                               int* __restrict__ node_list,
                                               int* __restrict__ off){
  __shared__ float smk[K_*64];
  __shared__ float smv[K_*K_];
  __shared__ int sroute[N_];
  int tid = threadIdx.x;
  for (int idx = tid; idx < K_*64; idx += 256){
    int kk = idx >> 6, d = idx & 63;
    float a = 0.f;
    for (int c = 0; c < 64; ++c) a += env_cb[kk*64+c] * w_k[c*64+d];
    smk[idx] = a;
  }
  for (int idx = tid; idx < K_*K_; idx += 256){
    int kk = idx / K_, j = idx % K_;
    float a = 0.f;
    for (int c = 0; c < 64; ++c) a += env_cb[kk*64+c] * w_v[c*K_+j];
    smv[idx] = a;
  }
  __syncthreads();
  for (int n = tid; n < N_; n += 256){
    float s[K_];
    float mx = -1e30f;
    for (int j = 0; j < K_; ++j){
      float a = 0.f;
      for (int d = 0; d < 64; ++d) a += matq[n*64+d]*smk[j*64+d];
      s[j] = a * 0.125f;
      mx = fmaxf(mx, s[j]);
    }
    float sum = 0.f;
    for (int j = 0; j < K_; ++j){ s[j] = expf(s[j]-mx); sum += s[j]; }
    float inv = 1.f/sum;
    int best = 0; float bestv = -1e30f;
    for (int j2 = 0; j2 < K_; ++j2){
      float lg = 0.f;
      for (int j = 0; j < K_; ++j) lg += s[j]*inv*smv[j*K_+j2];
      float tot = lg + gumbel_at((unsigned)(n*K_+j2));
      if (tot > bestv){ bestv = tot; best = j2; }
    }
    sroute[n] = best;
  }
  __syncthreads();
  if (tid == 0){
    int cnt[K_]; for (int j=0;j<K_;++j) cnt[j]=0;
    for (int n=0;n<N_;++n) cnt[sroute[n]]++;
    int acc=0;
    for (int j=0;j<K_;++j){ off[j]=acc; acc+=cnt[j]; }
    off[K_]=acc;
    int pos[K_]; for (int j=0;j<K_;++j) pos[j]=off[j];
    for (int n=0;n<N_;++n) node_list[pos[sroute[n]]++] = n;
  }
}

// ---------------- t_emb ----------------
__global__ void k_temb(const int* __restrict__ t_pos, float* __restrict__ temb){
  int tid = threadIdx.x;
  if (tid >= B_*T_) return;
  int b = tid / T_, t = tid % T_;
  int p0 = t_pos[(b*T_+t)*2+0], p1 = t_pos[(b*T_+t)*2+1];
  float tp = (float)((p0 <= 4) ? p1 : 23 + p1);
  float c0 = -logf(10000.f)/32.f;
  for (int j = 0; j < 32; ++j){
    float a = tp * expf(c0 * (float)j);
    temb[(b*T_+t)*64 + j]      = cosf(a);
    temb[(b*T_+t)*64 + 32 + j] = sinf(a);
  }
}

// ---------------- core[b] ----------------
__global__ __launch_bounds__(256) void k_core(const float* __restrict__ temb,
                                              const float* __restrict__ core_W,
                                              const float* __restrict__ core_b,
                                              float* __restrict__ core_f){
  int idx = blockIdx.x*256 + threadIdx.x;
  if (idx >= B_*4096) return;
  int b = idx >> 12, c = idx & 4095;
  const float* te = temb + (b*T_ + 11)*64;
  float a = core_b[c];
  for (int h = 0; h < 64; ++h) a += te[h] * core_W[h*4096 + c];
  core_f[idx] = a;
}

// ---------------- tmp1[b] ----------------
__global__ __launch_bounds__(256) void k_tmp1(const int* __restrict__ ind,
                                              const float* __restrict__ nv_p1,
                                              const float* __restrict__ nv_pk,
                                              float* __restrict__ tmp1){
  int idx = blockIdx.x*256 + threadIdx.x;
  if (idx >= B_*4096) return;
  int b = idx >> 12, c = idx & 4095;
  int i0 = ind[(b*T_+1)*2+0], i1 = ind[(b*T_+1)*2+1];
  int row = (i0 <= 4) ? i1 : 23 + i1;
  const float* te = nv_p1 + row*64;
  float a = 0.f;
  for (int h = 0; h < 64; ++h) a += te[h] * nv_pk[h*4096 + c];
  tmp1[idx] = a;
}

// ---------------- TCN stage-1 precompute ----------------
// AA[slot][3][128]: fused fcx rows through Win top half; TE[slot][b][t0..4][128]:
// temb through Win bottom half. h0 = x0*A0 + x1*A1 + C0 + TE[b][t] + bin.
__global__ __launch_bounds__(256) void k_tprep(
    const float* __restrict__ temb,
    const float* __restrict__ fcx_W, const float* __restrict__ fcx_b,
    const float* __restrict__ WinN, const float* __restrict__ WinP,
    float* __restrict__ TE)
{
  int slot = blockIdx.x;
  int k = slot >> 1, path = slot & 1;
  const float* Win = (path ? WinP : WinN) + k*16384;
  float* TEs = TE + slot*10240;
  float* AAs = TE + 20*10240 + slot*384;
  int tid = threadIdx.x;
  int o = tid & 127, half = tid >> 7;
  if (half == 0){
    float a0=0.f, a1=0.f, c0=0.f;
    for (int c = 0; c < 64; ++c){
      float w = Win[c*128 + o];
      a0 += fcx_W[c]*w; a1 += fcx_W[64+c]*w; c0 += fcx_b[c]*w;
    }
    AAs[o] = a0; AAs[128+o] = a1; AAs[256+o] = c0;
  }
  for (int p = half; p < 80; p += 2){
    int b = p/5, t = p%5;
    const float* te = temb + (b*T_ + t)*64;
    float acc = 0.f;
    for (int cc = 0; cc < 64; ++cc) acc += te[cc] * Win[(64+cc)*128 + o];
    TEs[p*128 + o] = acc;
  }
}

// ---------------- TCN v2: algebraic stage-1, LDS 21.3 KB ----------------
__global__ __launch_bounds__(256) void k_tcn2(
    const float* __restrict__ x,
    const float* __restrict__ TE,
    const int* __restrict__ node_list, const int* __restrict__ off,
    const float* __restrict__ binN,
    const float* __restrict__ WfN,  const float* __restrict__ bfN,
    const float* __restrict__ WgN,  const float* __restrict__ bgN,
    const float* __restrict__ WoutN,const float* __restrict__ boutN,
    const float* __restrict__ binP,
    const float* __restrict__ WfP,  const float* __restrict__ bfP,
    const float* __restrict__ WgP,  const float* __restrict__ bgP,
    const float* __restrict__ WoutP,const float* __restrict__ boutP,
    float* __restrict__ out_unb, float* __restrict__ out_hpr)
{
  int slot = blockIdx.x;
  int k = slot >> 1;
  int path = slot & 1;
  int cnt = off[k+1] - off[k];
  int rows = cnt * 16;
  int r0 = blockIdx.y * TROWS;
  if (r0 >= rows) return;

  const float* bin  = (path ? binP  : binN)  + k*128;
  const float* Wf   = (path ? WfP   : WfN)   + k*4*16384;
  const float* bf_  = (path ? bfP   : bfN)   + k*2*128;
  const float* Wg   = (path ? WgP   : WgN)   + k*4*16384;
  const float* bg_  = (path ? bgP   : bgN)   + k*2*128;
  const float* Wout = (path ? WoutP : WoutN) + k*8192;
  const float* bout = (path ? boutP : boutN) + k*64;
  float* outb = path ? out_hpr : out_unb;
  int t0 = path ? 0 : 1;

  __shared__ __align__(16) float sH0[TROWS*512];   // 24 rt x 128 (12 KB)
  __shared__ __align__(16) float sH1[TROWS*256];   // 12 x 128 (6 KB)
  __shared__ __align__(16) float sH2[TROWS*128];   // 6 x 128 (3 KB)
  __shared__ float xs[TROWS][4][2];
  __shared__ int rowBN[TROWS];
  __shared__ int rowB[TROWS];

  int tid = threadIdx.x;
  if (tid < TROWS){
    int r = r0 + tid;
    if (r < rows){
      int node = node_list[off[k] + (r >> 4)];
      int b = r & 15;
      rowBN[tid] = b*N_ + node;
      rowB[tid]  = b;
    } else { rowBN[tid] = -1; rowB[tid] = 0; }
  }
  __syncthreads();
  if (tid < TROWS*4){
    int i = tid >> 2, tl = tid & 3;
    int rb = rowBN[i];
    float x0 = 0.f, x1 = 0.f;
    if (rb >= 0){
      const float* xp = x + (rb*T_ + tl + t0)*2;
      x0 = xp[0]; x1 = xp[1];
    }
    xs[i][tl][0] = x0; xs[i][tl][1] = x1;
  }
  __syncthreads();

  // Stage 1 (algebraic): h0 = x0*A0 + x1*A1 + C0 + TE[b][tl+t0] + bin
  {
    int o = tid & 127, half = tid >> 7;
    const float* AAs = TE + 20*10240 + slot*384;
    const float* TEs = TE + slot*10240;
    float a0 = AAs[o], a1 = AAs[128+o], c0 = AAs[256+o];
    float bn = bin[o];
    #pragma unroll
    for (int jj = 0; jj < 12; ++jj){
      int rt = half*12 + jj;
      int i = rt >> 2, tl = rt & 3;
      float v = xs[i][tl][0]*a0 + xs[i][tl][1]*a1 + c0
              + TEs[(rowB[i]*5 + tl + t0)*128 + o] + bn;
      sH0[rt*128 + o] = v;
    }
  }
  __syncthreads();

  // Stage 2: block0 (d=1), fused f+g, 6 j per thread (12 total), sH0 -> sH1.
  {
    int o = tid & 127;
    int jg = (tid >> 7)*6;
    float af[6], ag[6];
    #pragma unroll
    for (int j=0;j<6;++j){ af[j]=0.f; ag[j]=0.f; }
    for (int c = 0; c < 128; c += 4){
      float f00=Wf[(c+0)*128+o], f01=Wf[(c+1)*128+o], f02=Wf[(c+2)*128+o], f03=Wf[(c+3)*128+o];
      float f10=Wf[16384+(c+0)*128+o], f11=Wf[16384+(c+1)*128+o], f12=Wf[16384+(c+2)*128+o], f13=Wf[16384+(c+3)*128+o];
      float g00=Wg[(c+0)*128+o], g01=Wg[(c+1)*128+o], g02=Wg[(c+2)*128+o], g03=Wg[(c+3)*128+o];
      float g10=Wg[16384+(c+0)*128+o], g11=Wg[16384+(c+1)*128+o], g12=Wg[16384+(c+2)*128+o], g13=Wg[16384+(c+3)*128+o];
      #pragma unroll
      for (int jj=0;jj<6;++jj){
        int j = jg + jj;
        int i = j >> 1, ti = j & 1;
        float4 xa = *(const float4*)&sH0[(i*4+ti*2  )*128 + c];
        float4 xb = *(const float4*)&sH0[(i*4+ti*2+1)*128 + c];
        af[jj] += xa.x*f00 + xa.y*f01 + xa.z*f02 + xa.w*f03
                + xb.x*f10 + xb.y*f11 + xb.z*f12 + xb.w*f13;
        ag[jj] += xa.x*g00 + xa.y*g01 + xa.z*g02 + xa.w*g03
                + xb.x*g10 + xb.y*g11 + xb.z*g12 + xb.w*g13;
      }
    }
    float bfv = bf_[o], bgv = bg_[o];
    #pragma unroll
    for (int jj=0;jj<6;++jj){
      int j = jg + jj;
      int i = j >> 1, ti = j & 1;
      float f = tanhf(af[jj] + bfv);
      float g = 1.f/(1.f + expf(-(ag[jj] + bgv)));
      sH1[j*128 + o] = f*g + sH0[(i*4 + ti*2 + 1)*128 + o];
    }
  }
  __syncthreads();

  // Stage 3: block1 (d=2), fused f+g, 3 i per thread (6 total), sH1 -> sH2.
  {
    int o = tid & 127;
    int ig = (tid >> 7)*3;
    const float* Wf1 = Wf + 2*16384;
    const float* Wg1 = Wg + 2*16384;
    float af[3], ag[3];
    #pragma unroll
    for (int i=0;i<3;++i){ af[i]=0.f; ag[i]=0.f; }
    for (int c = 0; c < 128; c += 4){
      float f00=Wf1[(c+0)*128+o], f01=Wf1[(c+1)*128+o], f02=Wf1[(c+2)*128+o], f03=Wf1[(c+3)*128+o];
      float f10=Wf1[16384+(c+0)*128+o], f11=Wf1[16384+(c+1)*128+o], f12=Wf1[16384+(c+2)*128+o], f13=Wf1[16384+(c+3)*128+o];
      float g00=Wg1[(c+0)*128+o], g01=Wg1[(c+1)*128+o], g02=Wg1[(c+2)*128+o], g03=Wg1[(c+3)*128+o];
      float g10=Wg1[16384+(c+0)*128+o], g11=Wg1[16384+(c+1)*128+o], g12=Wg1[16384+(c+2)*128+o], g13=Wg1[16384+(c+3)*128+o];
      #pragma unroll
      for (int ii=0;ii<3;++ii){
        int i = ig + ii;
        float4 xa = *(const float4*)&sH1[(i*2+0)*128 + c];
        float4 xb = *(const float4*)&sH1[(i*2+1)*128 + c];
        af[ii] += xa.x*f00 + xa.y*f01 + xa.z*f02 + xa.w*f03
                + xb.x*f10 + xb.y*f11 + xb.z*f12 + xb.w*f13;
        ag[ii] += xa.x*g00 + xa.y*g01 + xa.z*g02 + xa.w*g03
                + xb.x*g10 + xb.y*g11 + xb.z*g12 + xb.w*g13;
      }
    }
    float bfv = bf_[128+o], bgv = bg_[128+o];
    #pragma unroll
    for (int ii=0;ii<3;++ii){
      int i = ig + ii;
      float f = tanhf(af[ii] + bfv);
      float g = 1.f/(1.f + expf(-(ag[ii] + bgv)));
      sH2[i*128 + o] = f*g + sH1[(i*2+1)*128 + o];
    }
  }
  __syncthreads();

  // Stage 4: out = h2 @ Wout + bout (128 -> 64)
  {
    int o6 = tid & 63, grp = tid >> 6;
    #pragma unroll
    for (int ii=0; ii<2; ++ii){
      int i = grp*2 + ii;
      if (i >= TROWS) continue;
      float acc = 0.f;
      for (int c = 0; c < 128; c += 4){
        float w0=Wout[(c+0)*64+o6], w1=Wout[(c+1)*64+o6],
              w2=Wout[(c+2)*64+o6], w3=Wout[(c+3)*64+o6];
        float4 xv = *(const float4*)&sH2[i*128 + c];
        acc += xv.x*w0 + xv.y*w1 + xv.z*w2 + xv.w*w3;
      }
      if (rowBN[i] >= 0) outb[rowBN[i]*64 + o6] = acc + bout[o6];
    }
  }
}

// ---------------- fused per-expert TCN (round-13 fallback, used if !useP) ----------------
__global__ __launch_bounds__(256) void k_tcn(
    const float* __restrict__ x,
    const float* __restrict__ fcx_W, const float* __restrict__ fcx_b,
    const float* __restrict__ temb,
    const int* __restrict__ node_list, const int* __restrict__ off,
    const float* __restrict__ WinN, const float* __restrict__ binN,
    const float* __restrict__ WfN,  const float* __restrict__ bfN,
    const float* __restrict__ WgN,  const float* __restrict__ bgN,
    const float* __restrict__ WoutN,const float* __restrict__ boutN,
    const float* __restrict__ WinP, const float* __restrict__ binP,
    const float* __restrict__ WfP,  const float* __restrict__ bfP,
    const float* __restrict__ WgP,  const float* __restrict__ bgP,
    const float* __restrict__ WoutP,const float* __restrict__ boutP,
    float* __restrict__ out_unb, float* __restrict__ out_hpr)
{
  int slot = blockIdx.x;
  int k = slot >> 1;
  int path = slot & 1;
  int cnt = off[k+1] - off[k];
  int rows = cnt * 16;
  int r0 = blockIdx.y * TROWS;
  if (r0 >= rows) return;

  const float* Win  = (path ? WinP  : WinN)  + k*16384;
  const float* bin  = (path ? binP  : binN)  + k*128;
  const float* Wf   = (path ? WfP   : WfN)   + k*4*16384;
  const float* bf_  = (path ? bfP   : bfN)   + k*2*128;
  const float* Wg   = (path ? WgP   : WgN)   + k*4*16384;
  const float* bg_  = (path ? bgP   : bgN)   + k*2*128;
  const float* Wout = (path ? WoutP : WoutN) + k*8192;
  const float* bout = (path ? boutP : boutN) + k*64;
  float* outb = path ? out_hpr : out_unb;
  int t0 = path ? 0 : 1;

  __shared__ __align__(16) float sIn[TROWS*512];
  __shared__ __align__(16) float sH0[TROWS*512];
  __shared__ __align__(16) float sH1[TROWS*256];
  __shared__ __align__(16) float sH2[TROWS*128];
  __shared__ int rowBN[TROWS];
  __shared__ int rowB[TROWS];

  int tid = threadIdx.x;
  if (tid < TROWS){
    int r = r0 + tid;
    if (r < rows){
      int node = node_list[off[k] + (r >> 4)];
      int b = r & 15;
      rowBN[tid] = b*N_ + node;
      rowB[tid]  = b;
    } else { rowBN[tid] = -1; rowB[tid] = 0; }
  }
  __syncthreads();

  for (int i = 0; i < TROWS; ++i){
    int rb = rowBN[i], b = rowB[i];
    for (int c2 = tid; c2 < 512; c2 += 256){
      int t = (c2 >> 7) + t0, c = c2 & 127;
      float v = 0.f;
      if (rb >= 0){
        if (c < 64){
          const float* xp = x + (rb*T_ + t)*2;
          v = xp[0]*fcx_W[c] + xp[1]*fcx_W[64+c] + fcx_b[c];
        } else {
          v = temb[(b*T_ + t)*64 + (c-64)];
        }
      }
      sIn[i*512 + c2] = v;
    }
  }
  __syncthreads();

  {
    int oc = (tid & 63)*2;
    int jg = (tid >> 6)*6;
    float a0[6], a1[6];
    #pragma unroll
    for (int j=0;j<6;++j){ a0[j]=0.f; a1[j]=0.f; }
    for (int c = 0; c < 128; c += 4){
      float2 w0 = *(const float2*)(Win + (c+0)*128 + oc);
      float2 w1 = *(const float2*)(Win + (c+1)*128 + oc);
      float2 w2 = *(const float2*)(Win + (c+2)*128 + oc);
      float2 w3 = *(const float2*)(Win + (c+3)*128 + oc);
      #pragma unroll
      for (int j=0;j<6;++j){
        float4 xv = *(const float4*)&sIn[(jg+j)*128 + c];
        a0[j] += xv.x*w0.x + xv.y*w1.x + xv.z*w2.x + xv.w*w3.x;
        a1[j] += xv.x*w0.y + xv.y*w1.y + xv.z*w2.y + xv.w*w3.y;
      }
    }
    float b0v = bin[oc], b1v = bin[oc+1];
    #pragma unroll
    for (int j=0;j<6;++j){
      sH0[(jg+j)*128 + oc]   = a0[j] + b0v;
      sH0[(jg+j)*128 + oc+1] = a1[j] + b1v;
    }
  }
  __syncthreads();

  {
    int o = tid & 127;
    int jg = (tid >> 7)*6;
    float af[6], ag[6];
    #pragma unroll
    for (int j=0;j<6;++j){ af[j]=0.f; ag[j]=0.f; }
    for (int c = 0; c < 128; c += 4){
      float f00=Wf[(c+0)*128+o], f01=Wf[(c+1)*128+o], f02=Wf[(c+2)*128+o], f03=Wf[(c+3)*128+o];
      float f10=Wf[16384+(c+0)*128+o], f11=Wf[16384+(c+1)*128+o], f12=Wf[16384+(c+2)*128+o], f13=Wf[16384+(c+3)*128+o];
      float g00=Wg[(c+0)*128+o], g01=Wg[(c+1)*128+o], g02=Wg[(c+2)*128+o], g03=Wg[(c+3)*128+o];
      float g10=Wg[16384+(c+0)*128+o], g11=Wg[16384+(c+1)*128+o], g12=Wg[16384+(c+2)*128+o], g13=Wg[16384+(c+3)*128+o];
      #pragma unroll
      for (int jj=0;jj<6;++jj){
        int j = jg + jj;
        int i = j >> 1, ti = j & 1;
        float4 xa = *(const float4*)&sH0[(i*4+ti*2  )*128 + c];
        float4 xb = *(const float4*)&sH0[(i*4+ti*2+1)*128 + c];
        af[jj] += xa.x*f00 + xa.y*f01 + xa.z*f02 + xa.w*f03
                + xb.x*f10 + xb.y*f11 + xb.z*f12 + xb.w*f13;
        ag[jj] += xa.x*g00 + xa.y*g01 + xa.z*g02 + xa.w*g03
                + xb.x*g10 + xb.y*g11 + xb.z*g12 + xb.w*g13;
      }
    }
    float bfv = bf_[o], bgv = bg_[o];
    #pragma unroll
    for (int jj=0;jj<6;++jj){
      int j = jg + jj;
      int i = j >> 1, ti = j & 1;
      float f = tanhf(af[jj] + bfv);
      float g = 1.f/(1.f + expf(-(ag[jj] + bgv)));
      sH1[j*128 + o] = f*g + sH0[(i*4 + ti*2 + 1)*128 + o];
    }
  }
  __syncthreads();

  {
    int o = tid & 127;
    int ig = (tid >> 7)*3;
    const float* Wf1 = Wf + 2*16384;
    const float* Wg1 = Wg + 2*16384;
    float af[3], ag[3];
    #pragma unroll
    for (int i=0;i<3;++i){ af[i]=0.f; ag[i]=0.f; }
    for (int c = 0; c < 128; c += 4){
      float f00=Wf1[(c+0)*128+o], f01=Wf1[(c+1)*128+o], f02=Wf1[(c+2)*128+o], f03=Wf1[(c+3)*128+o];
      float f10=Wf1[16384+(c+0)*128+o], f11=Wf1[16384+(c+1)*128+o], f12=Wf1[16384+(c+2)*128+o], f13=Wf1[16384+(c+3)*128+o];
      float g00=Wg1[(c+0)*128+o], g01=Wg1[(c+1)*128+o], g02=Wg1[(c+2)*128+o], g03=Wg1[(c+3)*128+o];
      float g10=Wg1[16384+(c+0)*128+o], g11=Wg1[16384+(c+1)*128+o], g12=Wg1[16384+(c+2)*128+o], g13=Wg1[16384+(c+3)*128+o];
      #pragma unroll
      for (int ii=0;ii<3;++ii){
        int i = ig + ii;
        float4 xa = *(const float4*)&sH1[(i*2+0)*128 + c];
        float4 xb = *(const float4*)&sH1[(i*2+1)*128 + c];
        af[ii] += xa.x*f00 + xa.y*f01 + xa.z*f02 + xa.w*f03
                + xb.x*f10 + xb.y*f11 + xb.z*f12 + xb.w*f13;
        ag[ii] += xa.x*g00 + xa.y*g01 + xa.z*g02 + xa.w*g03
                + xb.x*g10 + xb.y*g11 + xb.z*g12 + xb.w*g13;
      }
    }
    float bfv = bf_[128+o], bgv = bg_[128+o];
    #pragma unroll
    for (int ii=0;ii<3;++ii){
      int i = ig + ii;
      float f = tanhf(af[ii] + bfv);
      float g = 1.f/(1.f + expf(-(ag[ii] + bgv)));
      sH2[i*128 + o] = f*g + sH1[(i*2+1)*128 + o];
    }
  }
  __syncthreads();

  {
    int o6 = tid & 63, grp = tid >> 6;
    #pragma unroll
    for (int ii=0; ii<2; ++ii){
      int i = grp*2 + ii;
      if (i >= TROWS) continue;
      float acc = 0.f;
      for (int c = 0; c < 128; c += 4){
        float w0=Wout[(c+0)*64+o6], w1=Wout[(c+1)*64+o6],
              w2=Wout[(c+2)*64+o6], w3=Wout[(c+3)*64+o6];
        float4 xv = *(const float4*)&sH2[i*128 + c];
        acc += xv.x*w0 + xv.y*w1 + xv.z*w2 + xv.w*w3;
      }
      if (rowBN[i] >= 0) outb[rowBN[i]*64 + o6] = acc + bout[o6];
    }
  }
}

// ---------------- batchnorm ----------------
__global__ __launch_bounds__(256) void k_bnstats(const float* __restrict__ unb,
                                                 const float* __restrict__ hpr,
                                                 float* __restrict__ stats){
  int bid = blockIdx.x;
  int tensor = bid >> 6, c = bid & 63;
  const float* buf = tensor ? hpr : unb;
  float s1 = 0.f, s2 = 0.f;
  for (int r = threadIdx.x; r < NROWS; r += 256){
    float v = buf[r*64 + c];
    s1 += v; s2 += v*v;
  }
  __shared__ float r1[256], r2[256];
  r1[threadIdx.x]=s1; r2[threadIdx.x]=s2;
  __syncthreads();
  for (int s=128; s>0; s>>=1){
    if (threadIdx.x < s){ r1[threadIdx.x]+=r1[threadIdx.x+s]; r2[threadIdx.x]+=r2[threadIdx.x+s]; }
    __syncthreads();
  }
  if (threadIdx.x==0){
    float mean = r1[0]/(float)NROWS;
    float var  = r2[0]/(float)NROWS - mean*mean;
    stats[tensor*128 + c]      = mean;
    stats[tensor*128 + 64 + c] = rsqrtf(var + 1e-5f);
  }
}

__global__ __launch_bounds__(256) void k_bnapply(float* __restrict__ unb, float* __restrict__ hpr,
                                                 const float* __restrict__ stats,
                                                 const float* __restrict__ g1, const float* __restrict__ be1,
                                                 const float* __restrict__ gP, const float* __restrict__ beP){
  int idx = blockIdx.x*256 + threadIdx.x;
  if (idx >= 2*NROWS*64) return;
  int tensor = idx >= NROWS*64;
  int local = idx - tensor*NROWS*64;
  int c = local & 63;
  float* buf = tensor ? hpr : unb;
  float mean = stats[tensor*128+c], rstd = stats[tensor*128+64+c];
  float g = tensor ? gP[c] : g1[c];
  float bb = tensor ? beP[c] : be1[c];
  buf[local] = g * (buf[local]-mean) * rstd + bb;
}

// ---------------- round-11 flash attn (proven; geo path + fallback) ----------------
template<int AMODE, int RELU, int FINAL, int ADD>
__global__ __launch_bounds__(256) void k_attn(
    const float* __restrict__ geo,
    const float* __restrict__ Qf, const float* __restrict__ Qb,
    const float* __restrict__ M,
    const float* __restrict__ Keysf, const float* __restrict__ Keysb,
    const float* __restrict__ X,
    const float* __restrict__ X0, const float* __restrict__ Z1,
    const float* __restrict__ Wg, const float* __restrict__ bg,
    float* __restrict__ cur, float* __restrict__ Y)
{
  __shared__ __align__(16) float kbuf[64][65];
  __shared__ __align__(16) float xbuf[64][64];
  __shared__ __align__(16) float vbuf[8][64];
  __shared__ __align__(16) float pbuf[8][64];

  int b = blockIdx.y, n0 = blockIdx.x*8;
  int tid = threadIdx.x;
  int nl = tid >> 5, ml = tid & 31;
  int n = n0 + nl;
  float rrK[16], rrX[16], rrA[2];

  if (AMODE != 0){
    for (int idx = tid; idx < 512; idx += 256){
      int r = idx >> 6, kk = idx & 63;
      int nn = n0 + r;
      float q = 0.f;
      if (nn < N_) q = (AMODE == 1) ? Qf[(b*N_+nn)*64+kk] : Qb[nn*64+kk];
      pbuf[r][kk] = q;
    }
    for (int idx = tid; idx < 4096; idx += 256)
      kbuf[idx>>6][idx&63] = M[b*4096 + idx];
    __syncthreads();
    float vx = 0.f, vy = 0.f;
    for (int kk = 0; kk < 64; ++kk){
      float q = pbuf[nl][kk];
      float2 m2 = *(const float2*)&kbuf[kk][ml*2];
      vx += q*m2.x; vy += q*m2.y;
    }
    __syncthreads();
    vbuf[nl][ml*2]   = vx;
    vbuf[nl][ml*2+1] = vy;
  }
  {
    if (AMODE != 0) __syncthreads();
    #pragma unroll
    for (int ii = 0; ii < 16; ++ii){
      int idx = tid + ii*256;
      int mm = idx >> 6, kk = idx & 63;
      if (AMODE != 0)
        kbuf[mm][kk] = (AMODE == 1) ? Keysf[(b*N_+mm)*64+kk] : Keysb[mm*64+kk];
      xbuf[mm][kk] = X[(b*N_+mm)*64+kk];
    }
    if (AMODE == 0){
      #pragma unroll
      for (int ii = 0; ii < 2; ++ii){
        int idx = tid + ii*256;
        int r = idx >> 6, mm = idx & 63;
        int nn = n0 + r;
        pbuf[r][mm] = (nn < N_) ? geo[nn*N_ + mm] : 0.f;
      }
    }
    __syncthreads();
  }

  float m_run = -1e30f, l_run = 0.f;
  float accx = 0.f, accy = 0.f;

  for (int ci = 0; ci < 8; ++ci){
    int m0 = ci*64;
    if (ci < 7){
      #pragma unroll
      for (int ii=0; ii<16; ++ii){
        int idx = tid + ii*256;
        int mm = idx >> 6, kk = idx & 63;
        int m = m0 + 64 + mm;
        if (AMODE != 0)
          rrK[ii] = (m < N_) ? ((AMODE == 1) ? Keysf[(b*N_+m)*64+kk] : Keysb[m*64+kk]) : 0.f;
        rrX[ii] = (m < N_) ? X[(b*N_+m)*64+kk] : 0.f;
      }
      if (AMODE == 0){
        #pragma unroll
        for (int ii=0; ii<2; ++ii){
          int idx = tid + ii*256;
          int r = idx >> 6, mm = idx & 63;
          int nn = n0 + r, m = m0 + 64 + mm;
          rrA[ii] = (nn < N_ && m < N_) ? geo[nn*N_ + m] : 0.f;
        }
      }
    }
    if (AMODE != 0){
      float s0 = 0.f, s1 = 0.f;
      for (int kk = 0; kk < 64; kk += 4){
        float4 qv = *(const float4*)&vbuf[nl][kk];
        float4 k0 = *(const float4*)&kbuf[ml   ][kk];
        float4 k1 = *(const float4*)&kbuf[ml+32][kk];
        s0 += qv.x*k0.x + qv.y*k0.y + qv.z*k0.z + qv.w*k0.w;
        s1 += qv.x*k1.x + qv.y*k1.y + qv.z*k1.z + qv.w*k1.w;
      }
      float v0 = (m0 + ml      < N_) ? (RELU ? fmaxf(s0, 0.f) : s0) : -1e30f;
      float v1 = (m0 + ml + 32 < N_) ? (RELU ? fmaxf(s1, 0.f) : s1) : -1e30f;
      float cmax = fmaxf(v0, v1);
      #pragma unroll
      for (int msk = 1; msk < 32; msk <<= 1) cmax = fmaxf(cmax, __shfl_xor(cmax, msk, 32));
      float mnew = fmaxf(m_run, cmax);
      float scale = expf(m_run - mnew);
      float p0 = expf(v0 - mnew);
      float p1 = expf(v1 - mnew);
      float lc = p0 + p1;
      #pragma unroll
      for (int msk = 1; msk < 32; msk <<= 1) lc += __shfl_xor(lc, msk, 32);
      l_run = l_run*scale + lc;
      m_run = mnew;
      accx *= scale; accy *= scale;
      pbuf[nl][ml]    = p0;
      pbuf[nl][ml+32] = p1;
    }
    __syncthreads();
    for (int mm = 0; mm < 64; mm += 4){
      float4 pv = *(const float4*)&pbuf[nl][mm];
      float2 x0 = *(const float2*)&xbuf[mm+0][ml*2];
      float2 x1 = *(const float2*)&xbuf[mm+1][ml*2];
      float2 x2 = *(const float2*)&xbuf[mm+2][ml*2];
      float2 x3 = *(const float2*)&xbuf[mm+3][ml*2];
      accx += pv.x*x0.x + pv.y*x1.x + pv.z*x2.x + pv.w*x3.x;
      accy += pv.x*x0.y + pv.y*x1.y + pv.z*x2.y + pv.w*x3.y;
    }
    __syncthreads();
    if (ci < 7){
      #pragma unroll
      for (int ii=0; ii<16; ++ii){
        int idx = tid + ii*256;
        int mm = idx >> 6, kk = idx & 63;
        if (AMODE != 0) kbuf[mm][kk] = rrK[ii];
        xbuf[mm][kk] = rrX[ii];
      }
      if (AMODE == 0){
        #pragma unroll
        for (int ii=0; ii<2; ++ii){
          int idx = tid + ii*256;
          pbuf[idx>>6][idx&63] = rrA[ii];
        }
      }
      __syncthreads();
    }
  }
  if (AMODE != 0){
    float inv = 1.f / l_run;
    accx *= inv; accy *= inv;
  }

  if (!FINAL){
    if (n < N_){
      float2 o2; o2.x = accx; o2.y = accy;
      *(float2*)&Y[(b*N_+n)*64 + ml*2] = o2;
    }
    return;
  }

  {
    int row = b*N_ + n;
    float svx = 0.f, svy = 0.f;
    if (n < N_){
      float2 x0v = *(const float2*)&X0[row*64 + ml*2];
      float2 z1v = *(const float2*)&Z1[row*64 + ml*2];
      svx = accx + x0v.x + z1v.x;
      svy = accy + x0v.y + z1v.y;
    }
    vbuf[nl][ml*2]   = svx;
    vbuf[nl][ml*2+1] = svy;
    for (int idx = tid; idx < 4096; idx += 256)
      kbuf[idx>>6][idx&63] = Wg[idx];
    __syncthreads();
    float ox = 0.f, oy = 0.f;
    for (int kk = 0; kk < 64; ++kk){
      float s = vbuf[nl][kk];
      float2 w2 = *(const float2*)&kbuf[kk][ml*2];
      ox += s*w2.x; oy += s*w2.y;
    }
    if (n < N_){
      float2 bv = *(const float2*)&bg[ml*2];
      float vx = ox + bv.x, vy = oy + bv.y;
      if (ADD){
        float2 old = *(const float2*)&cur[row*64 + ml*2];
        vx += old.x; vy += old.y;
      }
      float2 o2; o2.x = vx; o2.y = vy;
      *(float2*)&cur[row*64 + ml*2] = o2;
    }
  }
}

// ---------------- pass 1 with raw-score caching ----------------
template<int AMODE, int RELU>
__global__ __launch_bounds__(256) void k_attn_p1(
    const float* __restrict__ Qf, const float* __restrict__ Qb,
    const float* __restrict__ M,
    const float* __restrict__ Keysf, const float* __restrict__ Keysb,
    const float* __restrict__ X,
    float* __restrict__ Pb, float* __restrict__ Y)
{
  __shared__ __align__(16) float kbuf[64][65];
  __shared__ __align__(16) float xbuf[64][64];
  __shared__ __align__(16) float vbuf[8][64];
  __shared__ __align__(16) float pbuf[8][64];

  int b = blockIdx.y, n0 = blockIdx.x*8;
  int tid = threadIdx.x;
  int nl = tid >> 5, ml = tid & 31;
  int n = n0 + nl;
  float rrK[16], rrX[16];

  for (int idx = tid; idx < 512; idx += 256){
    int r = idx >> 6, kk = idx & 63;
    int nn = n0 + r;
    float q = 0.f;
    if (nn < N_) q = (AMODE == 1) ? Qf[(b*N_+nn)*64+kk] : Qb[nn*64+kk];
    pbuf[r][kk] = q;
  }
  for (int idx = tid; idx < 4096; idx += 256)
    kbuf[idx>>6][idx&63] = M[b*4096 + idx];
  __syncthreads();
  float vx = 0.f, vy = 0.f;
  for (int kk = 0; kk < 64; ++kk){
    float q = pbuf[nl][kk];
    float2 m2 = *(const float2*)&kbuf[kk][ml*2];
    vx += q*m2.x; vy += q*m2.y;
  }
  __syncthreads();
  vbuf[nl][ml*2]   = vx;
  vbuf[nl][ml*2+1] = vy;
  __syncthreads();
  #pragma unroll
  for (int ii = 0; ii < 16; ++ii){
    int idx = tid + ii*256;
    int mm = idx >> 6, kk = idx & 63;
    kbuf[mm][kk] = (AMODE == 1) ? Keysf[(b*N_+mm)*64+kk] : Keysb[mm*64+kk];
    xbuf[mm][kk] = X[(b*N_+mm)*64+kk];
  }
  __syncthreads();

  float m_run = -1e30f, l_run = 0.f;
  float accx = 0.f, accy = 0.f;

  for (int ci = 0; ci < 8; ++ci){
    int m0 = ci*64;
    if (ci < 7){
      #pragma unroll
      for (int ii=0; ii<16; ++ii){
        int idx = tid + ii*256;
        int mm = idx >> 6, kk = idx & 63;
        int m = m0 + 64 + mm;
        rrK[ii] = (m < N_) ? ((AMODE == 1) ? Keysf[(b*N_+m)*64+kk] : Keysb[m*64+kk]) : 0.f;
        rrX[ii] = (m < N_) ? X[(b*N_+m)*64+kk] : 0.f;
      }
    }
    {
      float s0 = 0.f, s1 = 0.f;
      for (int kk = 0; kk < 64; kk += 4){
        float4 qv = *(const float4*)&vbuf[nl][kk];
        float4 k0 = *(const float4*)&kbuf[ml   ][kk];
        float4 k1 = *(const float4*)&kbuf[ml+32][kk];
        s0 += qv.x*k0.x + qv.y*k0.y + qv.z*k0.z + qv.w*k0.w;
        s1 += qv.x*k1.x + qv.y*k1.y + qv.z*k1.z + qv.w*k1.w;
      }
      float v0 = (m0 + ml      < N_) ? (RELU ? fmaxf(s0, 0.f) : s0) : -1e30f;
      float v1 = (m0 + ml + 32 < N_) ? (RELU ? fmaxf(s1, 0.f) : s1) : -1e30f;
      if (n < N_){
        Pb[((long)(b*N_+n))*512 + m0 + ml]      = v0;
        Pb[((long)(b*N_+n))*512 + m0 + ml + 32] = v1;
      }
      float cmax = fmaxf(v0, v1);
      #pragma unroll
      for (int msk = 1; msk < 32; msk <<= 1) cmax = fmaxf(cmax, __shfl_xor(cmax, msk, 32));
      float mnew = fmaxf(m_run, cmax);
      float scale = expf(m_run - mnew);
      float p0 = expf(v0 - mnew);
      float p1 = expf(v1 - mnew);
      float lc = p0 + p1;
      #pragma unroll
      for (int msk = 1; msk < 32; msk <<= 1) lc += __shfl_xor(lc, msk, 32);
      l_run = l_run*scale + lc;
      m_run = mnew;
      accx *= scale; accy *= scale;
      pbuf[nl][ml]    = p0;
      pbuf[nl][ml+32] = p1;
    }
    __syncthreads();
    for (int mm = 0; mm < 64; mm += 4){
      float4 pv = *(const float4*)&pbuf[nl][mm];
      float2 x0 = *(const float2*)&xbuf[mm+0][ml*2];
      float2 x1 = *(const float2*)&xbuf[mm+1][ml*2];
      float2 x2 = *(const float2*)&xbuf[mm+2][ml*2];
      float2 x3 = *(const float2*)&xbuf[mm+3][ml*2];
      accx += pv.x*x0.x + pv.y*x1.x + pv.z*x2.x + pv.w*x3.x;
      accy += pv.x*x0.y + pv.y*x1.y + pv.z*x2.y + pv.w*x3.y;
    }
    __syncthreads();
    if (ci < 7){
      #pragma unroll
      for (int ii=0; ii<16; ++ii){
        int idx = tid + ii*256;
        kbuf[idx>>6][idx&63] = rrK[ii];
        xbuf[idx>>6][idx&63] = rrX[ii];
      }
      __syncthreads();
    }
  }
  float inv = 1.f / l_run;
  accx *= inv; accy *= inv;
  if (n < N_){
    float2 o2; o2.x = accx; o2.y = accy;
    *(float2*)&Y[(b*N_+n)*64 + ml*2] = o2;
  }
}

// ---------------- pass 2 from cached scores ----------------
template<int ADD>
__global__ __launch_bounds__(256) void k_attn_p2(
    const float* __restrict__ Pb,
    const float* __restrict__ X,      // zt1
    const float* __restrict__ X0,     // residual base
    const float* __restrict__ Wg, const float* __restrict__ bg,
    float* __restrict__ cur)
{
  __shared__ __align__(16) float pbuf[8][516];
  __shared__ __align__(16) float xbuf[64][64];
  __shared__ __align__(16) float vbuf[8][64];

  int b = blockIdx.y, n0 = blockIdx.x*8;
  int tid = threadIdx.x;
  int nl = tid >> 5, ml = tid & 31;
  int n = n0 + nl;
  float rrX[16];

  for (int idx = tid; idx < 8*512; idx += 256){
    int r = idx >> 9, m = idx & 511;
    int nn = n0 + r;
    pbuf[r][m] = (nn < N_) ? Pb[((long)(b*N_+nn))*512 + m] : -1e30f;
  }
  __syncthreads();
  float lmax = -1e30f;
  for (int m = ml; m < 512; m += 32) lmax = fmaxf(lmax, pbuf[nl][m]);
  #pragma unroll
  for (int msk=1; msk<32; msk<<=1) lmax = fmaxf(lmax, __shfl_xor(lmax, msk, 32));
  float lsum = 0.f;
  for (int m = ml; m < 512; m += 32){
    float p = expf(pbuf[nl][m] - lmax);
    pbuf[nl][m] = p;
    lsum += p;
  }
  #pragma unroll
  for (int msk=1; msk<32; msk<<=1) lsum += __shfl_xor(lsum, msk, 32);
  float inv = 1.f/lsum;
  for (int m = ml; m < 512; m += 32) pbuf[nl][m] *= inv;

  #pragma unroll
  for (int ii=0; ii<16; ++ii){
    int idx = tid + ii*256;
    int mm = idx>>6, kk = idx&63;
    xbuf[mm][kk] = X[(b*N_+mm)*64+kk];
  }
  __syncthreads();

  float accx = 0.f, accy = 0.f;
  for (int ci = 0; ci < 8; ++ci){
    int m0 = ci*64;
    if (ci < 7){
      #pragma unroll
      for (int ii=0; ii<16; ++ii){
        int idx = tid + ii*256;
        int mm = idx>>6, kk = idx&63;
        int m = m0+64+mm;
        rrX[ii] = (m < N_) ? X[(b*N_+m)*64+kk] : 0.f;
      }
    }
    for (int mm = 0; mm < 64; mm += 4){
      float4 pv = *(const float4*)&pbuf[nl][m0+mm];
      float2 x0 = *(const float2*)&xbuf[mm+0][ml*2];
      float2 x1 = *(const float2*)&xbuf[mm+1][ml*2];
      float2 x2 = *(const float2*)&xbuf[mm+2][ml*2];
      float2 x3 = *(const float2*)&xbuf[mm+3][ml*2];
      accx += pv.x*x0.x + pv.y*x1.x + pv.z*x2.x + pv.w*x3.x;
      accy += pv.x*x0.y + pv.y*x1.y + pv.z*x2.y + pv.w*x3.y;
    }
    __syncthreads();
    if (ci < 7){
      #pragma unroll
      for (int ii=0; ii<16; ++ii){
        int idx = tid + ii*256;
        xbuf[idx>>6][idx&63] = rrX[ii];
      }
      __syncthreads();
    }
  }

  {
    int row = b*N_ + n;
    float svx = 0.f, svy = 0.f;
    if (n < N_){
      float2 x0v = *(const float2*)&X0[row*64 + ml*2];
      float2 z1v = *(const float2*)&X[row*64 + ml*2];
      svx = accx + x0v.x + z1v.x;
      svy = accy + x0v.y + z1v.y;
    }
    vbuf[nl][ml*2]   = svx;
    vbuf[nl][ml*2+1] = svy;
    for (int idx = tid; idx < 4096; idx += 256)
      xbuf[idx>>6][idx&63] = Wg[idx];
    __syncthreads();
    float ox = 0.f, oy = 0.f;
    for (int kk = 0; kk < 64; ++kk){
      float s = vbuf[nl][kk];
      float2 w2 = *(const float2*)&xbuf[kk][ml*2];
      ox += s*w2.x; oy += s*w2.y;
    }
    if (n < N_){
      float2 bv = *(const float2*)&bg[ml*2];
      float vx = ox + bv.x, vy = oy + bv.y;
      if (ADD){
        float2 old = *(const float2*)&cur[row*64 + ml*2];
        vx += old.x; vy += old.y;
      }
      float2 o2; o2.x = vx; o2.y = vy;
      *(float2*)&cur[row*64 + ml*2] = o2;
    }
  }
}

// ---------------- output head ----------------
__global__ __launch_bounds__(128) void k_out(const float* __restrict__ cur,
                                             const float* __restrict__ W1, const float* __restrict__ bb1,
                                             const float* __restrict__ W2, const float* __restrict__ bb2,
                                             float* __restrict__ out){
  __shared__ float ch[4][64];
  __shared__ float hid[4*1200];
  int tid = threadIdx.x;
  int rbase = blockIdx.x*4;
  for (int idx = tid; idx < 256; idx += 128){
    int r = idx >> 6, h = idx & 63;
    ch[r][h] = cur[(rbase+r)*64 + h];
  }
  __syncthreads();
  for (int job = tid; job < 1200; job += 128){
    int t = job / 100, f = job - t*100;
    float a0 = bb1[t*100+f], a1 = a0, a2 = a0, a3 = a0;
    for (int h = 0; h < 64; ++h){
      float w = W1[(t*64+h)*100 + f];
      a0 += ch[0][h]*w; a1 += ch[1][h]*w; a2 += ch[2][h]*w; a3 += ch[3][h]*w;
    }
    hid[0*1200+job] = (a0 > 0.f) ? a0 : expm1f(a0);
    hid[1*1200+job] = (a1 > 0.f) ? a1 : expm1f(a1);
    hid[2*1200+job] = (a2 > 0.f) ? a2 : expm1f(a2);
    hid[3*1200+job] = (a3 > 0.f) ? a3 : expm1f(a3);
  }
  __syncthreads();
  if (tid < 96){
    int r = tid / 24, rem = tid % 24;
    int t = rem >> 1, o = rem & 1;
    float a = bb2[t*2+o];
    const float* hp = hid + r*1200 + t*100;
    for (int f = 0; f < 100; ++f) a += hp[f] * W2[(t*100+f)*2+o];
    out[(rbase+r)*24 + t*2+o] = a;
  }
}

// ---------------- launch ----------------
extern "C" void kernel_launch(void* const* d_in, const int* in_sizes, int n_in,
                              void* d_out, int out_size, void* d_ws, size_t ws_size,
                              hipStream_t stream)
{
  const float* x        = (const float*)d_in[0];
  const float* geo      = (const float*)d_in[2];
  const float* fcx_W    = (const float*)d_in[3];
  const float* fcx_b    = (const float*)d_in[4];
  const float* env_cb   = (const float*)d_in[5];
  const float* nodes_cb = (const float*)d_in[6];
  const float* w_v      = (const float*)d_in[7];
  const float* w_k      = (const float*)d_in[8];
  const float* w_q      = (const float*)d_in[9];
  const float* core_W   = (const float*)d_in[10];
  const float* core_b   = (const float*)d_in[11];
  const float* tN_Win   = (const float*)d_in[12];
  const float* tN_bin   = (const float*)d_in[13];
  const float* tN_Wf    = (const float*)d_in[14];
  const float* tN_bf    = (const float*)d_in[15];
  const float* tN_Wg    = (const float*)d_in[16];
  const float* tN_bg    = (const float*)d_in[17];
  const float* tN_Wout  = (const float*)d_in[18];
  const float* tN_bout  = (const float*)d_in[19];
  const float* tP_Win   = (const float*)d_in[20];
  const float* tP_bin   = (const float*)d_in[21];
  const float* tP_Wf    = (const float*)d_in[22];
  const float* tP_bf    = (const float*)d_in[23];
  const float* tP_Wg    = (const float*)d_in[24];
  const float* tP_bg    = (const float*)d_in[25];
  const float* tP_Wout  = (const float*)d_in[26];
  const float* tP_bout  = (const float*)d_in[27];
  const float* bn1_g    = (const float*)d_in[28];
  const float* bn1_b    = (const float*)d_in[29];
  const float* bnP_g    = (const float*)d_in[30];
  const float* bnP_b    = (const float*)d_in[31];
  const float* gcn1_W   = (const float*)d_in[32];
  const float* gcn1_b   = (const float*)d_in[33];
  const float* gcn2_W   = (const float*)d_in[34];
  const float* gcn2_b   = (const float*)d_in[35];
  const float* gcnp_W   = (const float*)d_in[36];
  const float* gcnp_b   = (const float*)d_in[37];
  const float* nv_p1    = (const float*)d_in[38];
  const float* nv_p2    = (const float*)d_in[39];
  const float* nv_p3    = (const float*)d_in[40];
  const float* nv_pk    = (const float*)d_in[41];
  const float* out_W1   = (const float*)d_in[42];
  const float* out_b1   = (const float*)d_in[43];
  const float* out_W2   = (const float*)d_in[44];
  const float* out_b2   = (const float*)d_in[45];
  const int*   t_pos    = (const int*)d_in[46];
  const int*   ind      = (const int*)d_in[47];

  // Base: 4096 B + 2,223,616 floats. Pb: +4,096,000 floats (gate 25.28 MB).
  // TE (212,480 floats) ALIASES Pb's start: consumed by k_tcn2 before p1 writes Pb.
  int* node_list = (int*)d_ws;
  int* off       = node_list + 512;
  float* F = (float*)((char*)d_ws + 4096);
  float* temb   = F + 0;
  float* core_f = F + 12288;
  float* tmp1   = F + 77824;
  float* stats  = F + 143360;
  float* matq   = F + 143616;
  float* unb    = F + 175616;
  float* hpr    = F + 687616;
  float* cur    = F + 1199616;
  float* zt1    = F + 1711616;
  float* Pb     = F + 2223616;
  float* TE     = Pb;            // alias (disjoint lifetimes)
  bool useP = ws_size >= (size_t)(4096 + (size_t)(2223616 + 4096000)*4);

  k_matq <<<dim3(125), dim3(256), 0, stream>>>(nodes_cb, w_q, matq);
  k_route<<<dim3(1),   dim3(256), 0, stream>>>(env_cb, w_v, w_k, matq, node_list, off);
  k_temb <<<dim3(1),   dim3(192), 0, stream>>>(t_pos, temb);
  k_core <<<dim3(256), dim3(256), 0, stream>>>(temb, core_W, core_b, core_f);
  if (useP){
    k_tprep<<<dim3(20), dim3(256), 0, stream>>>(temb, fcx_W, fcx_b, tN_Win, tP_Win, TE);
    k_tcn2 <<<dim3(20, 334), dim3(256), 0, stream>>>(x, TE, node_list, off,
        tN_bin, tN_Wf, tN_bf, tN_Wg, tN_bg, tN_Wout, tN_bout,
        tP_bin, tP_Wf, tP_bf, tP_Wg, tP_bg, tP_Wout, tP_bout,
        unb, hpr);
  } else {
    k_tcn  <<<dim3(20, 334), dim3(256), 0, stream>>>(x, fcx_W, fcx_b, temb, node_list, off,
        tN_Win, tN_bin, tN_Wf, tN_bf, tN_Wg, tN_bg, tN_Wout, tN_bout,
        tP_Win, tP_bin, tP_Wf, tP_bf, tP_Wg, tP_bg, tP_Wout, tP_bout,
        unb, hpr);
  }
  k_bnstats<<<dim3(128), dim3(256), 0, stream>>>(unb, hpr, stats);
  k_bnapply<<<dim3(4000),dim3(256), 0, stream>>>(unb, hpr, stats, bn1_g, bn1_b, bnP_g, bnP_b);
  k_tmp1<<<dim3(256), dim3(256), 0, stream>>>(ind, nv_p1, nv_pk, tmp1);

  dim3 ag(64, 16);
  const float* nil = nullptr;
  // gcn1: geo adjacency on h_prev
  k_attn<0,0,0,0><<<ag, 256, 0, stream>>>(geo, nil,nil,nil, nil,nil,
                                 hpr, nil,nil, nil,nil, nullptr, zt1);
  k_attn<0,0,1,0><<<ag, 256, 0, stream>>>(geo, nil,nil,nil, nil,nil,
                                 zt1, hpr, zt1, gcn1_W, gcn1_b, cur, nullptr);
  // gcn2: causal adjacency on unbias
  if (useP){
    k_attn_p1<1,0><<<ag, 256, 0, stream>>>(unb, nil, core_f, hpr, nil, unb, Pb, zt1);
    k_attn_p2<1>  <<<ag, 256, 0, stream>>>(Pb, zt1, unb, gcn2_W, gcn2_b, cur);
  } else {
    k_attn<1,0,0,0><<<ag, 256, 0, stream>>>(nil, unb,nil, core_f, hpr,nil,
                                   unb, nil,nil, nil,nil, nullptr, zt1);
    k_attn<1,0,1,1><<<ag, 256, 0, stream>>>(nil, unb,nil, core_f, hpr,nil,
                                   zt1, unb, zt1, gcn2_W, gcn2_b, cur, nullptr);
  }
  // gcnp: adaptive adjacency on unbias
  if (useP){
    k_attn_p1<2,1><<<ag, 256, 0, stream>>>(nil, nv_p2, tmp1, nil, nv_p3, unb, Pb, zt1);
    k_attn_p2<1>  <<<ag, 256, 0, stream>>>(Pb, zt1, unb, gcnp_W, gcnp_b, cur);
  } else {
    k_attn<2,1,0,0><<<ag, 256, 0, stream>>>(nil, nil,nv_p2, tmp1, nil,nv_p3,
                                   unb, nil,nil, nil,nil, nullptr, zt1);
    k_attn<2,1,1,1><<<ag, 256, 0, stream>>>(nil, nil,nv_p2, tmp1, nil,nv_p3,
                                   zt1, unb, zt1, gcnp_W, gcnp_b, cur, nullptr);
  }
  // head
  k_out<<<dim3(2000), dim3(128), 0, stream>>>(cur, out_W1, out_b1, out_W2, out_b2, (float*)d_out);
}

// Round 15
// 880.302 us; speedup vs baseline: 1.0768x; 1.0768x over previous
//
#include <hip/hip_runtime.h>
#include <hip/hip_bf16.h>
#include <math.h>

#define B_ 16
#define N_ 500
#define T_ 12
#define K_ 10
#define NROWS (B_*N_)   // 8000
#define TROWS 6         // k_tcn rows per block

// ---------------- threefry / gumbel (jax.random.key(42)) ----------------
__device__ __forceinline__ unsigned rotl32(unsigned v, int r){ return (v<<r)|(v>>(32-r)); }

__device__ __forceinline__ void threefry2x32(unsigned k0, unsigned k1,
                                             unsigned c0, unsigned c1,
                                             unsigned &o0, unsigned &o1){
  unsigned ks2 = k0 ^ k1 ^ 0x1BD11BDAu;
  unsigned x0 = c0 + k0, x1 = c1 + k1;
#define TF_R(r) { x0 += x1; x1 = rotl32(x1,(r)); x1 ^= x0; }
  TF_R(13) TF_R(15) TF_R(26) TF_R(6)
  x0 += k1;  x1 += ks2 + 1u;
  TF_R(17) TF_R(29) TF_R(16) TF_R(24)
  x0 += ks2; x1 += k0 + 2u;
  TF_R(13) TF_R(15) TF_R(26) TF_R(6)
  x0 += k0;  x1 += k1 + 3u;
  TF_R(17) TF_R(29) TF_R(16) TF_R(24)
  x0 += k1;  x1 += ks2 + 4u;
  TF_R(13) TF_R(15) TF_R(26) TF_R(6)
  x0 += ks2; x1 += k0 + 5u;
#undef TF_R
  o0 = x0; o1 = x1;
}

// Partitionable threefry (JAX >= 0.4.30): bits[i] = x0 ^ x1 of threefry(key,(0,i)).
// VERIFIED bit-exact vs harness (round 5 pass).
__device__ __forceinline__ float gumbel_at(unsigned idx){
  unsigned b0, b1;
  threefry2x32(0u, 42u, 0u, idx, b0, b1);
  unsigned bits = b0 ^ b1;
  float u = __uint_as_float((bits >> 9) | 0x3f800000u) - 1.0f;  // [0,1)
  u = fmaxf(u, 1.17549435e-38f);
  return -logf(-logf(u));
}

// ---------------- matq = nodes_cb @ w_q ----------------
__global__ __launch_bounds__(256) void k_matq(const float* __restrict__ nodes_cb,
                                              const float* __restrict__ w_q,
                                              float* __restrict__ matq){
  int idx = blockIdx.x*256 + threadIdx.x;
  if (idx >= N_*64) return;
  int n = idx >> 6, d = idx & 63;
  float a = 0.f;
  for (int c = 0; c < 64; ++c) a += nodes_cb[n*64+c] * w_q[c*64+d];
  matq[idx] = a;
}

// ---------------- routing ----------------
__global__ __launch_bounds__(256) void k_route(const float* __restrict__ env_cb,
                                               const float* __restrict__ w_v,
                                               const float* __restrict__ w_k,
                                               const float* __restrict__ matq,
                                               int* __restrict__ node_list,
                                               int* __restrict__ off){
  __shared__ float smk[K_*64];
  __shared__ float smv[K_*K_];
  __shared__ int sroute[N_];
  int tid = threadIdx.x;
  for (int idx = tid; idx < K_*64; idx += 256){
    int kk = idx >> 6, d = idx & 63;
    float a = 0.f;
    for (int c = 0; c < 64; ++c) a += env_cb[kk*64+c] * w_k[c*64+d];
    smk[idx] = a;
  }
  for (int idx = tid; idx < K_*K_; idx += 256){
    int kk = idx / K_, j = idx % K_;
    float a = 0.f;
    for (int c = 0; c < 64; ++c) a += env_cb[kk*64+c] * w_v[c*K_+j];
    smv[idx] = a;
  }
  __syncthreads();
  for (int n = tid; n < N_; n += 256){
    float s[K_];
    float mx = -1e30f;
    for (int j = 0; j < K_; ++j){
      float a = 0.f;
      for (int d = 0; d < 64; ++d) a += matq[n*64+d]*smk[j*64+d];
      s[j] = a * 0.125f;
      mx = fmaxf(mx, s[j]);
    }
    float sum = 0.f;
    for (int j = 0; j < K_; ++j){ s[j] = expf(s[j]-mx); sum += s[j]; }
    float inv = 1.f/sum;
    int best = 0; float bestv = -1e30f;
    for (int j2 = 0; j2 < K_; ++j2){
      float lg = 0.f;
      for (int j = 0; j < K_; ++j) lg += s[j]*inv*smv[j*K_+j2];
      float tot = lg + gumbel_at((unsigned)(n*K_+j2));
      if (tot > bestv){ bestv = tot; best = j2; }
    }
    sroute[n] = best;
  }
  __syncthreads();
  if (tid == 0){
    int cnt[K_]; for (int j=0;j<K_;++j) cnt[j]=0;
    for (int n=0;n<N_;++n) cnt[sroute[n]]++;
    int acc=0;
    for (int j=0;j<K_;++j){ off[j]=acc; acc+=cnt[j]; }
    off[K_]=acc;
    int pos[K_]; for (int j=0;j<K_;++j) pos[j]=off[j];
    for (int n=0;n<N_;++n) node_list[pos[sroute[n]]++] = n;
  }
}

// ---------------- t_emb ----------------
__global__ void k_temb(const int* __restrict__ t_pos, float* __restrict__ temb){
  int tid = threadIdx.x;
  if (tid >= B_*T_) return;
  int b = tid / T_, t = tid % T_;
  int p0 = t_pos[(b*T_+t)*2+0], p1 = t_pos[(b*T_+t)*2+1];
  float tp = (float)((p0 <= 4) ? p1 : 23 + p1);
  float c0 = -logf(10000.f)/32.f;
  for (int j = 0; j < 32; ++j){
    float a = tp * expf(c0 * (float)j);
    temb[(b*T_+t)*64 + j]      = cosf(a);
    temb[(b*T_+t)*64 + 32 + j] = sinf(a);
  }
}

// ---------------- core[b] ----------------
__global__ __launch_bounds__(256) void k_core(const float* __restrict__ temb,
                                              const float* __restrict__ core_W,
                                              const float* __restrict__ core_b,
                                              float* __restrict__ core_f){
  int idx = blockIdx.x*256 + threadIdx.x;
  if (idx >= B_*4096) return;
  int b = idx >> 12, c = idx & 4095;
  const float* te = temb + (b*T_ + 11)*64;
  float a = core_b[c];
  for (int h = 0; h < 64; ++h) a += te[h] * core_W[h*4096 + c];
  core_f[idx] = a;
}

// ---------------- tmp1[b] ----------------
__global__ __launch_bounds__(256) void k_tmp1(const int* __restrict__ ind,
                                              const float* __restrict__ nv_p1,
                                              const float* __restrict__ nv_pk,
                                              float* __restrict__ tmp1){
  int idx = blockIdx.x*256 + threadIdx.x;
  if (idx >= B_*4096) return;
  int b = idx >> 12, c = idx & 4095;
  int i0 = ind[(b*T_+1)*2+0], i1 = ind[(b*T_+1)*2+1];
  int row = (i0 <= 4) ? i1 : 23 + i1;
  const float* te = nv_p1 + row*64;
  float a = 0.f;
  for (int h = 0; h < 64; ++h) a += te[h] * nv_pk[h*4096 + c];
  tmp1[idx] = a;
}

// ---------------- TCN stage-1 precompute (PARALLEL: grid (20,81) x 128) ----------------
// y<80: TE[slot][p=y][o] = temb[b,t] @ Win_bottom (one output/thread, temb in LDS).
// y==80: AA[slot][{a0,a1,c0}][o] from fcx rows through Win_top.
__global__ __launch_bounds__(128) void k_tprep(
    const float* __restrict__ temb,
    const float* __restrict__ fcx_W, const float* __restrict__ fcx_b,
    const float* __restrict__ WinN, const float* __restrict__ WinP,
    float* __restrict__ TE)
{
  int slot = blockIdx.x;
  int y = blockIdx.y;
  int k = slot >> 1, path = slot & 1;
  const float* Win = (path ? WinP : WinN) + k*16384;
  int o = threadIdx.x;
  if (y < 80){
    __shared__ float ste[64];
    int b = y/5, t = y%5;
    if (o < 64) ste[o] = temb[(b*T_ + t)*64 + o];
    __syncthreads();
    float acc = 0.f;
    for (int cc = 0; cc < 64; ++cc) acc += ste[cc] * Win[(64+cc)*128 + o];
    TE[slot*10240 + y*128 + o] = acc;
  } else {
    float a0=0.f, a1=0.f, c0=0.f;
    for (int c = 0; c < 64; ++c){
      float w = Win[c*128 + o];
      a0 += fcx_W[c]*w; a1 += fcx_W[64+c]*w; c0 += fcx_b[c]*w;
    }
    float* AAs = TE + 20*10240 + slot*384;
    AAs[o] = a0; AAs[128+o] = a1; AAs[256+o] = c0;
  }
}

// ---------------- TCN v2: algebraic stage-1, LDS 21.3 KB ----------------
__global__ __launch_bounds__(256) void k_tcn2(
    const float* __restrict__ x,
    const float* __restrict__ TE,
    const int* __restrict__ node_list, const int* __restrict__ off,
    const float* __restrict__ binN,
    const float* __restrict__ WfN,  const float* __restrict__ bfN,
    const float* __restrict__ WgN,  const float* __restrict__ bgN,
    const float* __restrict__ WoutN,const float* __restrict__ boutN,
    const float* __restrict__ binP,
    const float* __restrict__ WfP,  const float* __restrict__ bfP,
    const float* __restrict__ WgP,  const float* __restrict__ bgP,
    const float* __restrict__ WoutP,const float* __restrict__ boutP,
    float* __restrict__ out_unb, float* __restrict__ out_hpr)
{
  int slot = blockIdx.x;
  int k = slot >> 1;
  int path = slot & 1;
  int cnt = off[k+1] - off[k];
  int rows = cnt * 16;
  int r0 = blockIdx.y * TROWS;
  if (r0 >= rows) return;

  const float* bin  = (path ? binP  : binN)  + k*128;
  const float* Wf   = (path ? WfP   : WfN)   + k*4*16384;
  const float* bf_  = (path ? bfP   : bfN)   + k*2*128;
  const float* Wg   = (path ? WgP   : WgN)   + k*4*16384;
  const float* bg_  = (path ? bgP   : bgN)   + k*2*128;
  const float* Wout = (path ? WoutP : WoutN) + k*8192;
  const float* bout = (path ? boutP : boutN) + k*64;
  float* outb = path ? out_hpr : out_unb;
  int t0 = path ? 0 : 1;

  __shared__ __align__(16) float sH0[TROWS*512];
  __shared__ __align__(16) float sH1[TROWS*256];
  __shared__ __align__(16) float sH2[TROWS*128];
  __shared__ float xs[TROWS][4][2];
  __shared__ int rowBN[TROWS];
  __shared__ int rowB[TROWS];

  int tid = threadIdx.x;
  if (tid < TROWS){
    int r = r0 + tid;
    if (r < rows){
      int node = node_list[off[k] + (r >> 4)];
      int b = r & 15;
      rowBN[tid] = b*N_ + node;
      rowB[tid]  = b;
    } else { rowBN[tid] = -1; rowB[tid] = 0; }
  }
  __syncthreads();
  if (tid < TROWS*4){
    int i = tid >> 2, tl = tid & 3;
    int rb = rowBN[i];
    float x0 = 0.f, x1 = 0.f;
    if (rb >= 0){
      const float* xp = x + (rb*T_ + tl + t0)*2;
      x0 = xp[0]; x1 = xp[1];
    }
    xs[i][tl][0] = x0; xs[i][tl][1] = x1;
  }
  __syncthreads();

  // Stage 1 (algebraic): h0 = x0*A0 + x1*A1 + C0 + TE[b][tl+t0] + bin
  {
    int o = tid & 127, half = tid >> 7;
    const float* AAs = TE + 20*10240 + slot*384;
    const float* TEs = TE + slot*10240;
    float a0 = AAs[o], a1 = AAs[128+o], c0 = AAs[256+o];
    float bn = bin[o];
    #pragma unroll
    for (int jj = 0; jj < 12; ++jj){
      int rt = half*12 + jj;
      int i = rt >> 2, tl = rt & 3;
      float v = xs[i][tl][0]*a0 + xs[i][tl][1]*a1 + c0
              + TEs[(rowB[i]*5 + tl + t0)*128 + o] + bn;
      sH0[rt*128 + o] = v;
    }
  }
  __syncthreads();

  // Stage 2: block0 (d=1), fused f+g, sH0 -> sH1.
  {
    int o = tid & 127;
    int jg = (tid >> 7)*6;
    float af[6], ag[6];
    #pragma unroll
    for (int j=0;j<6;++j){ af[j]=0.f; ag[j]=0.f; }
    for (int c = 0; c < 128; c += 4){
      float f00=Wf[(c+0)*128+o], f01=Wf[(c+1)*128+o], f02=Wf[(c+2)*128+o], f03=Wf[(c+3)*128+o];
      float f10=Wf[16384+(c+0)*128+o], f11=Wf[16384+(c+1)*128+o], f12=Wf[16384+(c+2)*128+o], f13=Wf[16384+(c+3)*128+o];
      float g00=Wg[(c+0)*128+o], g01=Wg[(c+1)*128+o], g02=Wg[(c+2)*128+o], g03=Wg[(c+3)*128+o];
      float g10=Wg[16384+(c+0)*128+o], g11=Wg[16384+(c+1)*128+o], g12=Wg[16384+(c+2)*128+o], g13=Wg[16384+(c+3)*128+o];
      #pragma unroll
      for (int jj=0;jj<6;++jj){
        int j = jg + jj;
        int i = j >> 1, ti = j & 1;
        float4 xa = *(const float4*)&sH0[(i*4+ti*2  )*128 + c];
        float4 xb = *(const float4*)&sH0[(i*4+ti*2+1)*128 + c];
        af[jj] += xa.x*f00 + xa.y*f01 + xa.z*f02 + xa.w*f03
                + xb.x*f10 + xb.y*f11 + xb.z*f12 + xb.w*f13;
        ag[jj] += xa.x*g00 + xa.y*g01 + xa.z*g02 + xa.w*g03
                + xb.x*g10 + xb.y*g11 + xb.z*g12 + xb.w*g13;
      }
    }
    float bfv = bf_[o], bgv = bg_[o];
    #pragma unroll
    for (int jj=0;jj<6;++jj){
      int j = jg + jj;
      int i = j >> 1, ti = j & 1;
      float f = tanhf(af[jj] + bfv);
      float g = 1.f/(1.f + expf(-(ag[jj] + bgv)));
      sH1[j*128 + o] = f*g + sH0[(i*4 + ti*2 + 1)*128 + o];
    }
  }
  __syncthreads();

  // Stage 3: block1 (d=2), fused f+g, sH1 -> sH2.
  {
    int o = tid & 127;
    int ig = (tid >> 7)*3;
    const float* Wf1 = Wf + 2*16384;
    const float* Wg1 = Wg + 2*16384;
    float af[3], ag[3];
    #pragma unroll
    for (int i=0;i<3;++i){ af[i]=0.f; ag[i]=0.f; }
    for (int c = 0; c < 128; c += 4){
      float f00=Wf1[(c+0)*128+o], f01=Wf1[(c+1)*128+o], f02=Wf1[(c+2)*128+o], f03=Wf1[(c+3)*128+o];
      float f10=Wf1[16384+(c+0)*128+o], f11=Wf1[16384+(c+1)*128+o], f12=Wf1[16384+(c+2)*128+o], f13=Wf1[16384+(c+3)*128+o];
      float g00=Wg1[(c+0)*128+o], g01=Wg1[(c+1)*128+o], g02=Wg1[(c+2)*128+o], g03=Wg1[(c+3)*128+o];
      float g10=Wg1[16384+(c+0)*128+o], g11=Wg1[16384+(c+1)*128+o], g12=Wg1[16384+(c+2)*128+o], g13=Wg1[16384+(c+3)*128+o];
      #pragma unroll
      for (int ii=0;ii<3;++ii){
        int i = ig + ii;
        float4 xa = *(const float4*)&sH1[(i*2+0)*128 + c];
        float4 xb = *(const float4*)&sH1[(i*2+1)*128 + c];
        af[ii] += xa.x*f00 + xa.y*f01 + xa.z*f02 + xa.w*f03
                + xb.x*f10 + xb.y*f11 + xb.z*f12 + xb.w*f13;
        ag[ii] += xa.x*g00 + xa.y*g01 + xa.z*g02 + xa.w*g03
                + xb.x*g10 + xb.y*g11 + xb.z*g12 + xb.w*g13;
      }
    }
    float bfv = bf_[128+o], bgv = bg_[128+o];
    #pragma unroll
    for (int ii=0;ii<3;++ii){
      int i = ig + ii;
      float f = tanhf(af[ii] + bfv);
      float g = 1.f/(1.f + expf(-(ag[ii] + bgv)));
      sH2[i*128 + o] = f*g + sH1[(i*2+1)*128 + o];
    }
  }
  __syncthreads();

  // Stage 4: out = h2 @ Wout + bout (128 -> 64)
  {
    int o6 = tid & 63, grp = tid >> 6;
    #pragma unroll
    for (int ii=0; ii<2; ++ii){
      int i = grp*2 + ii;
      if (i >= TROWS) continue;
      float acc = 0.f;
      for (int c = 0; c < 128; c += 4){
        float w0=Wout[(c+0)*64+o6], w1=Wout[(c+1)*64+o6],
              w2=Wout[(c+2)*64+o6], w3=Wout[(c+3)*64+o6];
        float4 xv = *(const float4*)&sH2[i*128 + c];
        acc += xv.x*w0 + xv.y*w1 + xv.z*w2 + xv.w*w3;
      }
      if (rowBN[i] >= 0) outb[rowBN[i]*64 + o6] = acc + bout[o6];
    }
  }
}

// ---------------- fused per-expert TCN (fallback when !useP) ----------------
__global__ __launch_bounds__(256) void k_tcn(
    const float* __restrict__ x,
    const float* __restrict__ fcx_W, const float* __restrict__ fcx_b,
    const float* __restrict__ temb,
    const int* __restrict__ node_list, const int* __restrict__ off,
    const float* __restrict__ WinN, const float* __restrict__ binN,
    const float* __restrict__ WfN,  const float* __restrict__ bfN,
    const float* __restrict__ WgN,  const float* __restrict__ bgN,
    const float* __restrict__ WoutN,const float* __restrict__ boutN,
    const float* __restrict__ WinP, const float* __restrict__ binP,
    const float* __restrict__ WfP,  const float* __restrict__ bfP,
    const float* __restrict__ WgP,  const float* __restrict__ bgP,
    const float* __restrict__ WoutP,const float* __restrict__ boutP,
    float* __restrict__ out_unb, float* __restrict__ out_hpr)
{
  int slot = blockIdx.x;
  int k = slot >> 1;
  int path = slot & 1;
  int cnt = off[k+1] - off[k];
  int rows = cnt * 16;
  int r0 = blockIdx.y * TROWS;
  if (r0 >= rows) return;

  const float* Win  = (path ? WinP  : WinN)  + k*16384;
  const float* bin  = (path ? binP  : binN)  + k*128;
  const float* Wf   = (path ? WfP   : WfN)   + k*4*16384;
  const float* bf_  = (path ? bfP   : bfN)   + k*2*128;
  const float* Wg   = (path ? WgP   : WgN)   + k*4*16384;
  const float* bg_  = (path ? bgP   : bgN)   + k*2*128;
  const float* Wout = (path ? WoutP : WoutN) + k*8192;
  const float* bout = (path ? boutP : boutN) + k*64;
  float* outb = path ? out_hpr : out_unb;
  int t0 = path ? 0 : 1;

  __shared__ __align__(16) float sIn[TROWS*512];
  __shared__ __align__(16) float sH0[TROWS*512];
  __shared__ __align__(16) float sH1[TROWS*256];
  __shared__ __align__(16) float sH2[TROWS*128];
  __shared__ int rowBN[TROWS];
  __shared__ int rowB[TROWS];

  int tid = threadIdx.x;
  if (tid < TROWS){
    int r = r0 + tid;
    if (r < rows){
      int node = node_list[off[k] + (r >> 4)];
      int b = r & 15;
      rowBN[tid] = b*N_ + node;
      rowB[tid]  = b;
    } else { rowBN[tid] = -1; rowB[tid] = 0; }
  }
  __syncthreads();

  for (int i = 0; i < TROWS; ++i){
    int rb = rowBN[i], b = rowB[i];
    for (int c2 = tid; c2 < 512; c2 += 256){
      int t = (c2 >> 7) + t0, c = c2 & 127;
      float v = 0.f;
      if (rb >= 0){
        if (c < 64){
          const float* xp = x + (rb*T_ + t)*2;
          v = xp[0]*fcx_W[c] + xp[1]*fcx_W[64+c] + fcx_b[c];
        } else {
          v = temb[(b*T_ + t)*64 + (c-64)];
        }
      }
      sIn[i*512 + c2] = v;
    }
  }
  __syncthreads();

  {
    int oc = (tid & 63)*2;
    int jg = (tid >> 6)*6;
    float a0[6], a1[6];
    #pragma unroll
    for (int j=0;j<6;++j){ a0[j]=0.f; a1[j]=0.f; }
    for (int c = 0; c < 128; c += 4){
      float2 w0 = *(const float2*)(Win + (c+0)*128 + oc);
      float2 w1 = *(const float2*)(Win + (c+1)*128 + oc);
      float2 w2 = *(const float2*)(Win + (c+2)*128 + oc);
      float2 w3 = *(const float2*)(Win + (c+3)*128 + oc);
      #pragma unroll
      for (int j=0;j<6;++j){
        float4 xv = *(const float4*)&sIn[(jg+j)*128 + c];
        a0[j] += xv.x*w0.x + xv.y*w1.x + xv.z*w2.x + xv.w*w3.x;
        a1[j] += xv.x*w0.y + xv.y*w1.y + xv.z*w2.y + xv.w*w3.y;
      }
    }
    float b0v = bin[oc], b1v = bin[oc+1];
    #pragma unroll
    for (int j=0;j<6;++j){
      sH0[(jg+j)*128 + oc]   = a0[j] + b0v;
      sH0[(jg+j)*128 + oc+1] = a1[j] + b1v;
    }
  }
  __syncthreads();

  {
    int o = tid & 127;
    int jg = (tid >> 7)*6;
    float af[6], ag[6];
    #pragma unroll
    for (int j=0;j<6;++j){ af[j]=0.f; ag[j]=0.f; }
    for (int c = 0; c < 128; c += 4){
      float f00=Wf[(c+0)*128+o], f01=Wf[(c+1)*128+o], f02=Wf[(c+2)*128+o], f03=Wf[(c+3)*128+o];
      float f10=Wf[16384+(c+0)*128+o], f11=Wf[16384+(c+1)*128+o], f12=Wf[16384+(c+2)*128+o], f13=Wf[16384+(c+3)*128+o];
      float g00=Wg[(c+0)*128+o], g01=Wg[(c+1)*128+o], g02=Wg[(c+2)*128+o], g03=Wg[(c+3)*128+o];
      float g10=Wg[16384+(c+0)*128+o], g11=Wg[16384+(c+1)*128+o], g12=Wg[16384+(c+2)*128+o], g13=Wg[16384+(c+3)*128+o];
      #pragma unroll
      for (int jj=0;jj<6;++jj){
        int j = jg + jj;
        int i = j >> 1, ti = j & 1;
        float4 xa = *(const float4*)&sH0[(i*4+ti*2  )*128 + c];
        float4 xb = *(const float4*)&sH0[(i*4+ti*2+1)*128 + c];
        af[jj] += xa.x*f00 + xa.y*f01 + xa.z*f02 + xa.w*f03
                + xb.x*f10 + xb.y*f11 + xb.z*f12 + xb.w*f13;
        ag[jj] += xa.x*g00 + xa.y*g01 + xa.z*g02 + xa.w*g03
                + xb.x*g10 + xb.y*g11 + xb.z*g12 + xb.w*g13;
      }
    }
    float bfv = bf_[o], bgv = bg_[o];
    #pragma unroll
    for (int jj=0;jj<6;++jj){
      int j = jg + jj;
      int i = j >> 1, ti = j & 1;
      float f = tanhf(af[jj] + bfv);
      float g = 1.f/(1.f + expf(-(ag[jj] + bgv)));
      sH1[j*128 + o] = f*g + sH0[(i*4 + ti*2 + 1)*128 + o];
    }
  }
  __syncthreads();

  {
    int o = tid & 127;
    int ig = (tid >> 7)*3;
    const float* Wf1 = Wf + 2*16384;
    const float* Wg1 = Wg + 2*16384;
    float af[3], ag[3];
    #pragma unroll
    for (int i=0;i<3;++i){ af[i]=0.f; ag[i]=0.f; }
    for (int c = 0; c < 128; c += 4){
      float f00=Wf1[(c+0)*128+o], f01=Wf1[(c+1)*128+o], f02=Wf1[(c+2)*128+o], f03=Wf1[(c+3)*128+o];
      float f10=Wf1[16384+(c+0)*128+o], f11=Wf1[16384+(c+1)*128+o], f12=Wf1[16384+(c+2)*128+o], f13=Wf1[16384+(c+3)*128+o];
      float g00=Wg1[(c+0)*128+o], g01=Wg1[(c+1)*128+o], g02=Wg1[(c+2)*128+o], g03=Wg1[(c+3)*128+o];
      float g10=Wg1[16384+(c+0)*128+o], g11=Wg1[16384+(c+1)*128+o], g12=Wg1[16384+(c+2)*128+o], g13=Wg1[16384+(c+3)*128+o];
      #pragma unroll
      for (int ii=0;ii<3;++ii){
        int i = ig + ii;
        float4 xa = *(const float4*)&sH1[(i*2+0)*128 + c];
        float4 xb = *(const float4*)&sH1[(i*2+1)*128 + c];
        af[ii] += xa.x*f00 + xa.y*f01 + xa.z*f02 + xa.w*f03
                + xb.x*f10 + xb.y*f11 + xb.z*f12 + xb.w*f13;
        ag[ii] += xa.x*g00 + xa.y*g01 + xa.z*g02 + xa.w*g03
                + xb.x*g10 + xb.y*g11 + xb.z*g12 + xb.w*g13;
      }
    }
    float bfv = bf_[128+o], bgv = bg_[128+o];
    #pragma unroll
    for (int ii=0;ii<3;++ii){
      int i = ig + ii;
      float f = tanhf(af[ii] + bfv);
      float g = 1.f/(1.f + expf(-(ag[ii] + bgv)));
      sH2[i*128 + o] = f*g + sH1[(i*2+1)*128 + o];
    }
  }
  __syncthreads();

  {
    int o6 = tid & 63, grp = tid >> 6;
    #pragma unroll
    for (int ii=0; ii<2; ++ii){
      int i = grp*2 + ii;
      if (i >= TROWS) continue;
      float acc = 0.f;
      for (int c = 0; c < 128; c += 4){
        float w0=Wout[(c+0)*64+o6], w1=Wout[(c+1)*64+o6],
              w2=Wout[(c+2)*64+o6], w3=Wout[(c+3)*64+o6];
        float4 xv = *(const float4*)&sH2[i*128 + c];
        acc += xv.x*w0 + xv.y*w1 + xv.z*w2 + xv.w*w3;
      }
      if (rowBN[i] >= 0) outb[rowBN[i]*64 + o6] = acc + bout[o6];
    }
  }
}

// ---------------- batchnorm ----------------
__global__ __launch_bounds__(256) void k_bnstats(const float* __restrict__ unb,
                                                 const float* __restrict__ hpr,
                                                 float* __restrict__ stats){
  int bid = blockIdx.x;
  int tensor = bid >> 6, c = bid & 63;
  const float* buf = tensor ? hpr : unb;
  float s1 = 0.f, s2 = 0.f;
  for (int r = threadIdx.x; r < NROWS; r += 256){
    float v = buf[r*64 + c];
    s1 += v; s2 += v*v;
  }
  __shared__ float r1[256], r2[256];
  r1[threadIdx.x]=s1; r2[threadIdx.x]=s2;
  __syncthreads();
  for (int s=128; s>0; s>>=1){
    if (threadIdx.x < s){ r1[threadIdx.x]+=r1[threadIdx.x+s]; r2[threadIdx.x]+=r2[threadIdx.x+s]; }
    __syncthreads();
  }
  if (threadIdx.x==0){
    float mean = r1[0]/(float)NROWS;
    float var  = r2[0]/(float)NROWS - mean*mean;
    stats[tensor*128 + c]      = mean;
    stats[tensor*128 + 64 + c] = rsqrtf(var + 1e-5f);
  }
}

__global__ __launch_bounds__(256) void k_bnapply(float* __restrict__ unb, float* __restrict__ hpr,
                                                 const float* __restrict__ stats,
                                                 const float* __restrict__ g1, const float* __restrict__ be1,
                                                 const float* __restrict__ gP, const float* __restrict__ beP){
  int idx = blockIdx.x*256 + threadIdx.x;
  if (idx >= 2*NROWS*64) return;
  int tensor = idx >= NROWS*64;
  int local = idx - tensor*NROWS*64;
  int c = local & 63;
  float* buf = tensor ? hpr : unb;
  float mean = stats[tensor*128+c], rstd = stats[tensor*128+64+c];
  float g = tensor ? gP[c] : g1[c];
  float bb = tensor ? beP[c] : be1[c];
  buf[local] = g * (buf[local]-mean) * rstd + bb;
}

// ---------------- round-11 flash attn (proven; geo path + fallback) ----------------
template<int AMODE, int RELU, int FINAL, int ADD>
__global__ __launch_bounds__(256) void k_attn(
    const float* __restrict__ geo,
    const float* __restrict__ Qf, const float* __restrict__ Qb,
    const float* __restrict__ M,
    const float* __restrict__ Keysf, const float* __restrict__ Keysb,
    const float* __restrict__ X,
    const float* __restrict__ X0, const float* __restrict__ Z1,
    const float* __restrict__ Wg, const float* __restrict__ bg,
    float* __restrict__ cur, float* __restrict__ Y)
{
  __shared__ __align__(16) float kbuf[64][65];
  __shared__ __align__(16) float xbuf[64][64];
  __shared__ __align__(16) float vbuf[8][64];
  __shared__ __align__(16) float pbuf[8][64];

  int b = blockIdx.y, n0 = blockIdx.x*8;
  int tid = threadIdx.x;
  int nl = tid >> 5, ml = tid & 31;
  int n = n0 + nl;
  float rrK[16], rrX[16], rrA[2];

  if (AMODE != 0){
    for (int idx = tid; idx < 512; idx += 256){
      int r = idx >> 6, kk = idx & 63;
      int nn = n0 + r;
      float q = 0.f;
      if (nn < N_) q = (AMODE == 1) ? Qf[(b*N_+nn)*64+kk] : Qb[nn*64+kk];
      pbuf[r][kk] = q;
    }
    for (int idx = tid; idx < 4096; idx += 256)
      kbuf[idx>>6][idx&63] = M[b*4096 + idx];
    __syncthreads();
    float vx = 0.f, vy = 0.f;
    for (int kk = 0; kk < 64; ++kk){
      float q = pbuf[nl][kk];
      float2 m2 = *(const float2*)&kbuf[kk][ml*2];
      vx += q*m2.x; vy += q*m2.y;
    }
    __syncthreads();
    vbuf[nl][ml*2]   = vx;
    vbuf[nl][ml*2+1] = vy;
  }
  {
    if (AMODE != 0) __syncthreads();
    #pragma unroll
    for (int ii = 0; ii < 16; ++ii){
      int idx = tid + ii*256;
      int mm = idx >> 6, kk = idx & 63;
      if (AMODE != 0)
        kbuf[mm][kk] = (AMODE == 1) ? Keysf[(b*N_+mm)*64+kk] : Keysb[mm*64+kk];
      xbuf[mm][kk] = X[(b*N_+mm)*64+kk];
    }
    if (AMODE == 0){
      #pragma unroll
      for (int ii = 0; ii < 2; ++ii){
        int idx = tid + ii*256;
        int r = idx >> 6, mm = idx & 63;
        int nn = n0 + r;
        pbuf[r][mm] = (nn < N_) ? geo[nn*N_ + mm] : 0.f;
      }
    }
    __syncthreads();
  }

  float m_run = -1e30f, l_run = 0.f;
  float accx = 0.f, accy = 0.f;

  for (int ci = 0; ci < 8; ++ci){
    int m0 = ci*64;
    if (ci < 7){
      #pragma unroll
      for (int ii=0; ii<16; ++ii){
        int idx = tid + ii*256;
        int mm = idx >> 6, kk = idx & 63;
        int m = m0 + 64 + mm;
        if (AMODE != 0)
          rrK[ii] = (m < N_) ? ((AMODE == 1) ? Keysf[(b*N_+m)*64+kk] : Keysb[m*64+kk]) : 0.f;
        rrX[ii] = (m < N_) ? X[(b*N_+m)*64+kk] : 0.f;
      }
      if (AMODE == 0){
        #pragma unroll
        for (int ii=0; ii<2; ++ii){
          int idx = tid + ii*256;
          int r = idx >> 6, mm = idx & 63;
          int nn = n0 + r, m = m0 + 64 + mm;
          rrA[ii] = (nn < N_ && m < N_) ? geo[nn*N_ + m] : 0.f;
        }
      }
    }
    if (AMODE != 0){
      float s0 = 0.f, s1 = 0.f;
      for (int kk = 0; kk < 64; kk += 4){
        float4 qv = *(const float4*)&vbuf[nl][kk];
        float4 k0 = *(const float4*)&kbuf[ml   ][kk];
        float4 k1 = *(const float4*)&kbuf[ml+32][kk];
        s0 += qv.x*k0.x + qv.y*k0.y + qv.z*k0.z + qv.w*k0.w;
        s1 += qv.x*k1.x + qv.y*k1.y + qv.z*k1.z + qv.w*k1.w;
      }
      float v0 = (m0 + ml      < N_) ? (RELU ? fmaxf(s0, 0.f) : s0) : -1e30f;
      float v1 = (m0 + ml + 32 < N_) ? (RELU ? fmaxf(s1, 0.f) : s1) : -1e30f;
      float cmax = fmaxf(v0, v1);
      #pragma unroll
      for (int msk = 1; msk < 32; msk <<= 1) cmax = fmaxf(cmax, __shfl_xor(cmax, msk, 32));
      float mnew = fmaxf(m_run, cmax);
      float scale = expf(m_run - mnew);
      float p0 = expf(v0 - mnew);
      float p1 = expf(v1 - mnew);
      float lc = p0 + p1;
      #pragma unroll
      for (int msk = 1; msk < 32; msk <<= 1) lc += __shfl_xor(lc, msk, 32);
      l_run = l_run*scale + lc;
      m_run = mnew;
      accx *= scale; accy *= scale;
      pbuf[nl][ml]    = p0;
      pbuf[nl][ml+32] = p1;
    }
    __syncthreads();
    for (int mm = 0; mm < 64; mm += 4){
      float4 pv = *(const float4*)&pbuf[nl][mm];
      float2 x0 = *(const float2*)&xbuf[mm+0][ml*2];
      float2 x1 = *(const float2*)&xbuf[mm+1][ml*2];
      float2 x2 = *(const float2*)&xbuf[mm+2][ml*2];
      float2 x3 = *(const float2*)&xbuf[mm+3][ml*2];
      accx += pv.x*x0.x + pv.y*x1.x + pv.z*x2.x + pv.w*x3.x;
      accy += pv.x*x0.y + pv.y*x1.y + pv.z*x2.y + pv.w*x3.y;
    }
    __syncthreads();
    if (ci < 7){
      #pragma unroll
      for (int ii=0; ii<16; ++ii){
        int idx = tid + ii*256;
        int mm = idx >> 6, kk = idx & 63;
        if (AMODE != 0) kbuf[mm][kk] = rrK[ii];
        xbuf[mm][kk] = rrX[ii];
      }
      if (AMODE == 0){
        #pragma unroll
        for (int ii=0; ii<2; ++ii){
          int idx = tid + ii*256;
          pbuf[idx>>6][idx&63] = rrA[ii];
        }
      }
      __syncthreads();
    }
  }
  if (AMODE != 0){
    float inv = 1.f / l_run;
    accx *= inv; accy *= inv;
  }

  if (!FINAL){
    if (n < N_){
      float2 o2; o2.x = accx; o2.y = accy;
      *(float2*)&Y[(b*N_+n)*64 + ml*2] = o2;
    }
    return;
  }

  {
    int row = b*N_ + n;
    float svx = 0.f, svy = 0.f;
    if (n < N_){
      float2 x0v = *(const float2*)&X0[row*64 + ml*2];
      float2 z1v = *(const float2*)&Z1[row*64 + ml*2];
      svx = accx + x0v.x + z1v.x;
      svy = accy + x0v.y + z1v.y;
    }
    vbuf[nl][ml*2]   = svx;
    vbuf[nl][ml*2+1] = svy;
    for (int idx = tid; idx < 4096; idx += 256)
      kbuf[idx>>6][idx&63] = Wg[idx];
    __syncthreads();
    float ox = 0.f, oy = 0.f;
    for (int kk = 0; kk < 64; ++kk){
      float s = vbuf[nl][kk];
      float2 w2 = *(const float2*)&kbuf[kk][ml*2];
      ox += s*w2.x; oy += s*w2.y;
    }
    if (n < N_){
      float2 bv = *(const float2*)&bg[ml*2];
      float vx = ox + bv.x, vy = oy + bv.y;
      if (ADD){
        float2 old = *(const float2*)&cur[row*64 + ml*2];
        vx += old.x; vy += old.y;
      }
      float2 o2; o2.x = vx; o2.y = vy;
      *(float2*)&cur[row*64 + ml*2] = o2;
    }
  }
}

// ---------------- pass 1 with raw-score caching ----------------
template<int AMODE, int RELU>
__global__ __launch_bounds__(256) void k_attn_p1(
    const float* __restrict__ Qf, const float* __restrict__ Qb,
    const float* __restrict__ M,
    const float* __restrict__ Keysf, const float* __restrict__ Keysb,
    const float* __restrict__ X,
    float* __restrict__ Pb, float* __restrict__ Y)
{
  __shared__ __align__(16) float kbuf[64][65];
  __shared__ __align__(16) float xbuf[64][64];
  __shared__ __align__(16) float vbuf[8][64];
  __shared__ __align__(16) float pbuf[8][64];

  int b = blockIdx.y, n0 = blockIdx.x*8;
  int tid = threadIdx.x;
  int nl = tid >> 5, ml = tid & 31;
  int n = n0 + nl;
  float rrK[16], rrX[16];

  for (int idx = tid; idx < 512; idx += 256){
    int r = idx >> 6, kk = idx & 63;
    int nn = n0 + r;
    float q = 0.f;
    if (nn < N_) q = (AMODE == 1) ? Qf[(b*N_+nn)*64+kk] : Qb[nn*64+kk];
    pbuf[r][kk] = q;
  }
  for (int idx = tid; idx < 4096; idx += 256)
    kbuf[idx>>6][idx&63] = M[b*4096 + idx];
  __syncthreads();
  float vx = 0.f, vy = 0.f;
  for (int kk = 0; kk < 64; ++kk){
    float q = pbuf[nl][kk];
    float2 m2 = *(const float2*)&kbuf[kk][ml*2];
    vx += q*m2.x; vy += q*m2.y;
  }
  __syncthreads();
  vbuf[nl][ml*2]   = vx;
  vbuf[nl][ml*2+1] = vy;
  __syncthreads();
  #pragma unroll
  for (int ii = 0; ii < 16; ++ii){
    int idx = tid + ii*256;
    int mm = idx >> 6, kk = idx & 63;
    kbuf[mm][kk] = (AMODE == 1) ? Keysf[(b*N_+mm)*64+kk] : Keysb[mm*64+kk];
    xbuf[mm][kk] = X[(b*N_+mm)*64+kk];
  }
  __syncthreads();

  float m_run = -1e30f, l_run = 0.f;
  float accx = 0.f, accy = 0.f;

  for (int ci = 0; ci < 8; ++ci){
    int m0 = ci*64;
    if (ci < 7){
      #pragma unroll
      for (int ii=0; ii<16; ++ii){
        int idx = tid + ii*256;
        int mm = idx >> 6, kk = idx & 63;
        int m = m0 + 64 + mm;
        rrK[ii] = (m < N_) ? ((AMODE == 1) ? Keysf[(b*N_+m)*64+kk] : Keysb[m*64+kk]) : 0.f;
        rrX[ii] = (m < N_) ? X[(b*N_+m)*64+kk] : 0.f;
      }
    }
    {
      float s0 = 0.f, s1 = 0.f;
      for (int kk = 0; kk < 64; kk += 4){
        float4 qv = *(const float4*)&vbuf[nl][kk];
        float4 k0 = *(const float4*)&kbuf[ml   ][kk];
        float4 k1 = *(const float4*)&kbuf[ml+32][kk];
        s0 += qv.x*k0.x + qv.y*k0.y + qv.z*k0.z + qv.w*k0.w;
        s1 += qv.x*k1.x + qv.y*k1.y + qv.z*k1.z + qv.w*k1.w;
      }
      float v0 = (m0 + ml      < N_) ? (RELU ? fmaxf(s0, 0.f) : s0) : -1e30f;
      float v1 = (m0 + ml + 32 < N_) ? (RELU ? fmaxf(s1, 0.f) : s1) : -1e30f;
      if (n < N_){
        Pb[((long)(b*N_+n))*512 + m0 + ml]      = v0;
        Pb[((long)(b*N_+n))*512 + m0 + ml + 32] = v1;
      }
      float cmax = fmaxf(v0, v1);
      #pragma unroll
      for (int msk = 1; msk < 32; msk <<= 1) cmax = fmaxf(cmax, __shfl_xor(cmax, msk, 32));
      float mnew = fmaxf(m_run, cmax);
      float scale = expf(m_run - mnew);
      float p0 = expf(v0 - mnew);
      float p1 = expf(v1 - mnew);
      float lc = p0 + p1;
      #pragma unroll
      for (int msk = 1; msk < 32; msk <<= 1) lc += __shfl_xor(lc, msk, 32);
      l_run = l_run*scale + lc;
      m_run = mnew;
      accx *= scale; accy *= scale;
      pbuf[nl][ml]    = p0;
      pbuf[nl][ml+32] = p1;
    }
    __syncthreads();
    for (int mm = 0; mm < 64; mm += 4){
      float4 pv = *(const float4*)&pbuf[nl][mm];
      float2 x0 = *(const float2*)&xbuf[mm+0][ml*2];
      float2 x1 = *(const float2*)&xbuf[mm+1][ml*2];
      float2 x2 = *(const float2*)&xbuf[mm+2][ml*2];
      float2 x3 = *(const float2*)&xbuf[mm+3][ml*2];
      accx += pv.x*x0.x + pv.y*x1.x + pv.z*x2.x + pv.w*x3.x;
      accy += pv.x*x0.y + pv.y*x1.y + pv.z*x2.y + pv.w*x3.y;
    }
    __syncthreads();
    if (ci < 7){
      #pragma unroll
      for (int ii=0; ii<16; ++ii){
        int idx = tid + ii*256;
        kbuf[idx>>6][idx&63] = rrK[ii];
        xbuf[idx>>6][idx&63] = rrX[ii];
      }
      __syncthreads();
    }
  }
  float inv = 1.f / l_run;
  accx *= inv; accy *= inv;
  if (n < N_){
    float2 o2; o2.x = accx; o2.y = accy;
    *(float2*)&Y[(b*N_+n)*64 + ml*2] = o2;
  }
}

// ---------------- pass 2 from cached scores ----------------
template<int ADD>
__global__ __launch_bounds__(256) void k_attn_p2(
    const float* __restrict__ Pb,
    const float* __restrict__ X,      // zt1
    const float* __restrict__ X0,     // residual base
    const float* __restrict__ Wg, const float* __restrict__ bg,
    float* __restrict__ cur)
{
  __shared__ __align__(16) float pbuf[8][516];
  __shared__ __align__(16) float xbuf[64][64];
  __shared__ __align__(16) float vbuf[8][64];

  int b = blockIdx.y, n0 = blockIdx.x*8;
  int tid = threadIdx.x;
  int nl = tid >> 5, ml = tid & 31;
  int n = n0 + nl;
  float rrX[16];

  for (int idx = tid; idx < 8*512; idx += 256){
    int r = idx >> 9, m = idx & 511;
    int nn = n0 + r;
    pbuf[r][m] = (nn < N_) ? Pb[((long)(b*N_+nn))*512 + m] : -1e30f;
  }
  __syncthreads();
  float lmax = -1e30f;
  for (int m = ml; m < 512; m += 32) lmax = fmaxf(lmax, pbuf[nl][m]);
  #pragma unroll
  for (int msk=1; msk<32; msk<<=1) lmax = fmaxf(lmax, __shfl_xor(lmax, msk, 32));
  float lsum = 0.f;
  for (int m = ml; m < 512; m += 32){
    float p = expf(pbuf[nl][m] - lmax);
    pbuf[nl][m] = p;
    lsum += p;
  }
  #pragma unroll
  for (int msk=1; msk<32; msk<<=1) lsum += __shfl_xor(lsum, msk, 32);
  float inv = 1.f/lsum;
  for (int m = ml; m < 512; m += 32) pbuf[nl][m] *= inv;

  #pragma unroll
  for (int ii=0; ii<16; ++ii){
    int idx = tid + ii*256;
    int mm = idx>>6, kk = idx&63;
    xbuf[mm][kk] = X[(b*N_+mm)*64+kk];
  }
  __syncthreads();

  float accx = 0.f, accy = 0.f;
  for (int ci = 0; ci < 8; ++ci){
    int m0 = ci*64;
    if (ci < 7){
      #pragma unroll
      for (int ii=0; ii<16; ++ii){
        int idx = tid + ii*256;
        int mm = idx>>6, kk = idx&63;
        int m = m0+64+mm;
        rrX[ii] = (m < N_) ? X[(b*N_+m)*64+kk] : 0.f;
      }
    }
    for (int mm = 0; mm < 64; mm += 4){
      float4 pv = *(const float4*)&pbuf[nl][m0+mm];
      float2 x0 = *(const float2*)&xbuf[mm+0][ml*2];
      float2 x1 = *(const float2*)&xbuf[mm+1][ml*2];
      float2 x2 = *(const float2*)&xbuf[mm+2][ml*2];
      float2 x3 = *(const float2*)&xbuf[mm+3][ml*2];
      accx += pv.x*x0.x + pv.y*x1.x + pv.z*x2.x + pv.w*x3.x;
      accy += pv.x*x0.y + pv.y*x1.y + pv.z*x2.y + pv.w*x3.y;
    }
    __syncthreads();
    if (ci < 7){
      #pragma unroll
      for (int ii=0; ii<16; ++ii){
        int idx = tid + ii*256;
        xbuf[idx>>6][idx&63] = rrX[ii];
      }
      __syncthreads();
    }
  }

  {
    int row = b*N_ + n;
    float svx = 0.f, svy = 0.f;
    if (n < N_){
      float2 x0v = *(const float2*)&X0[row*64 + ml*2];
      float2 z1v = *(const float2*)&X[row*64 + ml*2];
      svx = accx + x0v.x + z1v.x;
      svy = accy + x0v.y + z1v.y;
    }
    vbuf[nl][ml*2]   = svx;
    vbuf[nl][ml*2+1] = svy;
    for (int idx = tid; idx < 4096; idx += 256)
      xbuf[idx>>6][idx&63] = Wg[idx];
    __syncthreads();
    float ox = 0.f, oy = 0.f;
    for (int kk = 0; kk < 64; ++kk){
      float s = vbuf[nl][kk];
      float2 w2 = *(const float2*)&xbuf[kk][ml*2];
      ox += s*w2.x; oy += s*w2.y;
    }
    if (n < N_){
      float2 bv = *(const float2*)&bg[ml*2];
      float vx = ox + bv.x, vy = oy + bv.y;
      if (ADD){
        float2 old = *(const float2*)&cur[row*64 + ml*2];
        vx += old.x; vy += old.y;
      }
      float2 o2; o2.x = vx; o2.y = vy;
      *(float2*)&cur[row*64 + ml*2] = o2;
    }
  }
}

// ---------------- output head ----------------
__global__ __launch_bounds__(128) void k_out(const float* __restrict__ cur,
                                             const float* __restrict__ W1, const float* __restrict__ bb1,
                                             const float* __restrict__ W2, const float* __restrict__ bb2,
                                             float* __restrict__ out){
  __shared__ float ch[4][64];
  __shared__ float hid[4*1200];
  int tid = threadIdx.x;
  int rbase = blockIdx.x*4;
  for (int idx = tid; idx < 256; idx += 128){
    int r = idx >> 6, h = idx & 63;
    ch[r][h] = cur[(rbase+r)*64 + h];
  }
  __syncthreads();
  for (int job = tid; job < 1200; job += 128){
    int t = job / 100, f = job - t*100;
    float a0 = bb1[t*100+f], a1 = a0, a2 = a0, a3 = a0;
    for (int h = 0; h < 64; ++h){
      float w = W1[(t*64+h)*100 + f];
      a0 += ch[0][h]*w; a1 += ch[1][h]*w; a2 += ch[2][h]*w; a3 += ch[3][h]*w;
    }
    hid[0*1200+job] = (a0 > 0.f) ? a0 : expm1f(a0);
    hid[1*1200+job] = (a1 > 0.f) ? a1 : expm1f(a1);
    hid[2*1200+job] = (a2 > 0.f) ? a2 : expm1f(a2);
    hid[3*1200+job] = (a3 > 0.f) ? a3 : expm1f(a3);
  }
  __syncthreads();
  if (tid < 96){
    int r = tid / 24, rem = tid % 24;
    int t = rem >> 1, o = rem & 1;
    float a = bb2[t*2+o];
    const float* hp = hid + r*1200 + t*100;
    for (int f = 0; f < 100; ++f) a += hp[f] * W2[(t*100+f)*2+o];
    out[(rbase+r)*24 + t*2+o] = a;
  }
}

// ---------------- launch ----------------
extern "C" void kernel_launch(void* const* d_in, const int* in_sizes, int n_in,
                              void* d_out, int out_size, void* d_ws, size_t ws_size,
                              hipStream_t stream)
{
  const float* x        = (const float*)d_in[0];
  const float* geo      = (const float*)d_in[2];
  const float* fcx_W    = (const float*)d_in[3];
  const float* fcx_b    = (const float*)d_in[4];
  const float* env_cb   = (const float*)d_in[5];
  const float* nodes_cb = (const float*)d_in[6];
  const float* w_v      = (const float*)d_in[7];
  const float* w_k      = (const float*)d_in[8];
  const float* w_q      = (const float*)d_in[9];
  const float* core_W   = (const float*)d_in[10];
  const float* core_b   = (const float*)d_in[11];
  const float* tN_Win   = (const float*)d_in[12];
  const float* tN_bin   = (const float*)d_in[13];
  const float* tN_Wf    = (const float*)d_in[14];
  const float* tN_bf    = (const float*)d_in[15];
  const float* tN_Wg    = (const float*)d_in[16];
  const float* tN_bg    = (const float*)d_in[17];
  const float* tN_Wout  = (const float*)d_in[18];
  const float* tN_bout  = (const float*)d_in[19];
  const float* tP_Win   = (const float*)d_in[20];
  const float* tP_bin   = (const float*)d_in[21];
  const float* tP_Wf    = (const float*)d_in[22];
  const float* tP_bf    = (const float*)d_in[23];
  const float* tP_Wg    = (const float*)d_in[24];
  const float* tP_bg    = (const float*)d_in[25];
  const float* tP_Wout  = (const float*)d_in[26];
  const float* tP_bout  = (const float*)d_in[27];
  const float* bn1_g    = (const float*)d_in[28];
  const float* bn1_b    = (const float*)d_in[29];
  const float* bnP_g    = (const float*)d_in[30];
  const float* bnP_b    = (const float*)d_in[31];
  const float* gcn1_W   = (const float*)d_in[32];
  const float* gcn1_b   = (const float*)d_in[33];
  const float* gcn2_W   = (const float*)d_in[34];
  const float* gcn2_b   = (const float*)d_in[35];
  const float* gcnp_W   = (const float*)d_in[36];
  const float* gcnp_b   = (const float*)d_in[37];
  const float* nv_p1    = (const float*)d_in[38];
  const float* nv_p2    = (const float*)d_in[39];
  const float* nv_p3    = (const float*)d_in[40];
  const float* nv_pk    = (const float*)d_in[41];
  const float* out_W1   = (const float*)d_in[42];
  const float* out_b1   = (const float*)d_in[43];
  const float* out_W2   = (const float*)d_in[44];
  const float* out_b2   = (const float*)d_in[45];
  const int*   t_pos    = (const int*)d_in[46];
  const int*   ind      = (const int*)d_in[47];

  // Base: 4096 B + 2,223,616 floats. Pb: +4,096,000 floats (gate 25.28 MB).
  // TE (212,480 floats) ALIASES Pb's start: consumed by k_tcn2 before p1 writes Pb.
  int* node_list = (int*)d_ws;
  int* off       = node_list + 512;
  float* F = (float*)((char*)d_ws + 4096);
  float* temb   = F + 0;
  float* core_f = F + 12288;
  float* tmp1   = F + 77824;
  float* stats  = F + 143360;
  float* matq   = F + 143616;
  float* unb    = F + 175616;
  float* hpr    = F + 687616;
  float* cur    = F + 1199616;
  float* zt1    = F + 1711616;
  float* Pb     = F + 2223616;
  float* TE     = Pb;            // alias (disjoint lifetimes)
  bool useP = ws_size >= (size_t)(4096 + (size_t)(2223616 + 4096000)*4);

  k_matq <<<dim3(125), dim3(256), 0, stream>>>(nodes_cb, w_q, matq);
  k_route<<<dim3(1),   dim3(256), 0, stream>>>(env_cb, w_v, w_k, matq, node_list, off);
  k_temb <<<dim3(1),   dim3(192), 0, stream>>>(t_pos, temb);
  k_core <<<dim3(256), dim3(256), 0, stream>>>(temb, core_W, core_b, core_f);
  if (useP){
    k_tprep<<<dim3(20, 81), dim3(128), 0, stream>>>(temb, fcx_W, fcx_b, tN_Win, tP_Win, TE);
    k_tcn2 <<<dim3(20, 334), dim3(256), 0, stream>>>(x, TE, node_list, off,
        tN_bin, tN_Wf, tN_bf, tN_Wg, tN_bg, tN_Wout, tN_bout,
        tP_bin, tP_Wf, tP_bf, tP_Wg, tP_bg, tP_Wout, tP_bout,
        unb, hpr);
  } else {
    k_tcn  <<<dim3(20, 334), dim3(256), 0, stream>>>(x, fcx_W, fcx_b, temb, node_list, off,
        tN_Win, tN_bin, tN_Wf, tN_bf, tN_Wg, tN_bg, tN_Wout, tN_bout,
        tP_Win, tP_bin, tP_Wf, tP_bf, tP_Wg, tP_bg, tP_Wout, tP_bout,
        unb, hpr);
  }
  k_bnstats<<<dim3(128), dim3(256), 0, stream>>>(unb, hpr, stats);
  k_bnapply<<<dim3(4000),dim3(256), 0, stream>>>(unb, hpr, stats, bn1_g, bn1_b, bnP_g, bnP_b);
  k_tmp1<<<dim3(256), dim3(256), 0, stream>>>(ind, nv_p1, nv_pk, tmp1);

  dim3 ag(64, 16);
  const float* nil = nullptr;
  // gcn1: geo adjacency on h_prev
  k_attn<0,0,0,0><<<ag, 256, 0, stream>>>(geo, nil,nil,nil, nil,nil,
                                 hpr, nil,nil, nil,nil, nullptr, zt1);
  k_attn<0,0,1,0><<<ag, 256, 0, stream>>>(geo, nil,nil,nil, nil,nil,
                                 zt1, hpr, zt1, gcn1_W, gcn1_b, cur, nullptr);
  // gcn2: causal adjacency on unbias
  if (useP){
    k_attn_p1<1,0><<<ag, 256, 0, stream>>>(unb, nil, core_f, hpr, nil, unb, Pb, zt1);
    k_attn_p2<1>  <<<ag, 256, 0, stream>>>(Pb, zt1, unb, gcn2_W, gcn2_b, cur);
  } else {
    k_attn<1,0,0,0><<<ag, 256, 0, stream>>>(nil, unb,nil, core_f, hpr,nil,
                                   unb, nil,nil, nil,nil, nullptr, zt1);
    k_attn<1,0,1,1><<<ag, 256, 0, stream>>>(nil, unb,nil, core_f, hpr,nil,
                                   zt1, unb, zt1, gcn2_W, gcn2_b, cur, nullptr);
  }
  // gcnp: adaptive adjacency on unbias
  if (useP){
    k_attn_p1<2,1><<<ag, 256, 0, stream>>>(nil, nv_p2, tmp1, nil, nv_p3, unb, Pb, zt1);
    k_attn_p2<1>  <<<ag, 256, 0, stream>>>(Pb, zt1, unb, gcnp_W, gcnp_b, cur);
  } else {
    k_attn<2,1,0,0><<<ag, 256, 0, stream>>>(nil, nil,nv_p2, tmp1, nil,nv_p3,
                                   unb, nil,nil, nil,nil, nullptr, zt1);
    k_attn<2,1,1,1><<<ag, 256, 0, stream>>>(nil, nil,nv_p2, tmp1, nil,nv_p3,
                                   zt1, unb, zt1, gcnp_W, gcnp_b, cur, nullptr);
  }
  // head
  k_out<<<dim3(2000), dim3(128), 0, stream>>>(cur, out_W1, out_b1, out_W2, out_b2, (float*)d_out);
}